// Round 5
// baseline (452.106 us; speedup 1.0000x reference)
//
#include <hip/hip_runtime.h>
#include <cstddef>

typedef float f32x4 __attribute__((ext_vector_type(4)));
typedef __bf16 bf16x8 __attribute__((ext_vector_type(8)));
typedef unsigned short u16;
typedef unsigned short u16x4 __attribute__((ext_vector_type(4)));

__device__ __forceinline__ u16 f2bf(float f) {
  unsigned u = __builtin_bit_cast(unsigned, f);
  u += 0x7FFFu + ((u >> 16) & 1u);   // RNE round to bf16
  return (u16)(u >> 16);
}
__device__ __forceinline__ float bf2f(u16 b) {
  unsigned u = ((unsigned)b) << 16;
  return __builtin_bit_cast(float, u);
}
__device__ __forceinline__ float sigf(float x) { return 1.0f / (1.0f + __expf(-x)); }
__device__ __forceinline__ float tanhfast(float x) { return 1.0f - 2.0f / (__expf(2.0f * x) + 1.0f); }

// Raw barrier: LDS-only drain (lgkmcnt), NO vmcnt drain. sched_barrier(0)
// stops post-barrier code hoisting (rule #18).
__device__ __forceinline__ void wg_barrier() {
  asm volatile("s_waitcnt lgkmcnt(0)" ::: "memory");
  __builtin_amdgcn_s_barrier();
  __builtin_amdgcn_sched_barrier(0);
}

// ---------------------------------------------------------------------------
// K1: xprojT[dir][l][n][b] = e(tok[b][l]) . wih[dir][n][:] + bih[n] + bhh[n]
//   Row order m' = l*32 + b so the per-step slab [n][b] is contiguous for k2.
// ---------------------------------------------------------------------------
#define K1_LDA 328
__global__ __launch_bounds__(256) void k1_xproj(
    const int* __restrict__ tok1, const int* __restrict__ tok2,
    const float* __restrict__ embed,
    const float* __restrict__ wihA, const float* __restrict__ wihB,
    const float* __restrict__ wihC, const float* __restrict__ wihD,
    const float* __restrict__ bihA, const float* __restrict__ bihB,
    const float* __restrict__ bihC, const float* __restrict__ bihD,
    const float* __restrict__ bhhA, const float* __restrict__ bhhB,
    const float* __restrict__ bhhC, const float* __restrict__ bhhD,
    float* __restrict__ xprojT)
{
  __shared__ __align__(16) u16 aL[128 * K1_LDA];
  __shared__ __align__(16) u16 bL[64 * K1_LDA];
  const int dir = blockIdx.y;
  const float* wih = (dir == 0) ? wihA : (dir == 1) ? wihB : (dir == 2) ? wihC : wihD;
  const float* bih = (dir == 0) ? bihA : (dir == 1) ? bihB : (dir == 2) ? bihC : bihD;
  const float* bhh = (dir == 0) ? bhhA : (dir == 1) ? bhhB : (dir == 2) ? bhhC : bhhD;
  const int* tok = (dir < 2) ? tok1 : tok2;
  const int lb = blockIdx.x * 4;            // first l of this block (4 l's)
  const int tid = threadIdx.x;

  // stage A once: 128 rows (m' = row, l = lb + row/32, b = row%32)
  #pragma unroll
  for (int it = 0; it < 40; ++it) {
    const int idx = it * 256 + tid;
    const int row = idx / 80, k = (idx % 80) * 4;
    u16x4 o = {0, 0, 0, 0};
    if (k < 300) {
      const int bb = row & 31, ll = lb + (row >> 5);
      const long ar = (long)tok[bb * 128 + ll] * 300;
      const f32x4 v = *(const f32x4*)(embed + ar + k);
      o[0] = f2bf(v[0]); o[1] = f2bf(v[1]); o[2] = f2bf(v[2]); o[3] = f2bf(v[3]);
    }
    *(u16x4*)(aL + row * K1_LDA + k) = o;
  }

  const int lane = tid & 63, w = tid >> 6;  // wave w covers rows w*32..w*32+31
  const int lr = lane & 15, kg = lane >> 4;
  const u16* a0 = aL + (w * 32 + lr) * K1_LDA + kg * 8;
  const u16* b0 = bL + lr * K1_LDA + kg * 8;
  const int l = lb + w;                      // one l per wave

  for (int nc = 0; nc < 7; ++nc) {
    __syncthreads();                         // prev chunk MFMA done (bL free)
    #pragma unroll
    for (int it = 0; it < 20; ++it) {        // stage B chunk: 64 n-rows
      const int idx = it * 256 + tid;
      const int row = idx / 80, k = (idx % 80) * 4;
      const int n = nc * 64 + row;
      u16x4 o = {0, 0, 0, 0};
      if (k < 300 && n < 400) {
        const f32x4 v = *(const f32x4*)(wih + (long)n * 300 + k);
        o[0] = f2bf(v[0]); o[1] = f2bf(v[1]); o[2] = f2bf(v[2]); o[3] = f2bf(v[3]);
      }
      *(u16x4*)(bL + row * K1_LDA + k) = o;
    }
    __syncthreads();

    f32x4 acc[2][4];
    #pragma unroll
    for (int mt = 0; mt < 2; ++mt)
      #pragma unroll
      for (int nt = 0; nt < 4; ++nt) acc[mt][nt] = 0.f;
    #pragma unroll
    for (int ks = 0; ks < 10; ++ks) {
      bf16x8 af[2], bfv[4];
      #pragma unroll
      for (int mt = 0; mt < 2; ++mt) af[mt] = *(const bf16x8*)(a0 + mt * 16 * K1_LDA + ks * 32);
      #pragma unroll
      for (int nt = 0; nt < 4; ++nt) bfv[nt] = *(const bf16x8*)(b0 + nt * 16 * K1_LDA + ks * 32);
      #pragma unroll
      for (int mt = 0; mt < 2; ++mt)
        #pragma unroll
        for (int nt = 0; nt < 4; ++nt)
          acc[mt][nt] = __builtin_amdgcn_mfma_f32_16x16x32_bf16(af[mt], bfv[nt], acc[mt][nt], 0, 0, 0);
    }
    // store: lane r-values = 4 consecutive b at fixed (l, n) -> f32x4
    #pragma unroll
    for (int nt = 0; nt < 4; ++nt) {
      const int n = nc * 64 + nt * 16 + lr;
      if (n < 400) {
        const float bias = bih[n] + bhh[n];
        #pragma unroll
        for (int mt = 0; mt < 2; ++mt) {
          const int b0i = mt * 16 + kg * 4;  // batch offset of reg 0
          f32x4 o;
          #pragma unroll
          for (int r = 0; r < 4; ++r) o[r] = acc[mt][nt][r] + bias;
          *(f32x4*)(xprojT + (((long)dir * 128 + l) * 400 + n) * 32 + b0i) = o;
        }
      }
    }
  }
}

// ---------------------------------------------------------------------------
// K2: recurrent LSTM via batched MFMA with GATE-INTERLEAVED row permutation.
//   Permuted weight row' = 4*j + gate  (orig row = gate*100 + j). Then for
//   lane (lr=b, kg), m-tile mt: accumulator reg r = gate-r pre-act of hidden
//   unit j = mt*4+kg, batch b. Gates compute IN-REGISTER on MFMA output:
//   no gT round-trip, no thread reshuffle. h double-buffered in LDS ->
//   ONE lgkm-only barrier per step. whh A-frags in registers all 128 steps.
//   xprojT prefetched 2 steps deep (vmcnt never drained at barrier).
// ---------------------------------------------------------------------------
__global__ __launch_bounds__(512, 2) void k2_lstm(
    const float* __restrict__ xprojT,
    const float* __restrict__ whhA, const float* __restrict__ whhB,
    const float* __restrict__ whhC, const float* __restrict__ whhD,
    u16* __restrict__ s1e, u16* __restrict__ s2e)
{
  const int bh = blockIdx.x;                 // batch half (0: b 0-15, 1: b 16-31)
  const int dir = blockIdx.y;
  const float* whh = (dir == 0) ? whhA : (dir == 1) ? whhB : (dir == 2) ? whhC : whhD;
  const int tid = threadIdx.x;
  const int lane = tid & 63, wave = tid >> 6;
  const int lr = lane & 15, kg = lane >> 4;

  __shared__ __align__(16) u16 hB[2][16][136];  // h bf16 (B^T layout), dbuf

  // ---- whh A-fragments (one-time). Wave w owns m-tiles mt = w + 8i.
  //      A tile row lr = permuted row mt*16+lr = 4j+g with j = mt*4 + lr/4,
  //      g = lr%4  ->  orig whh row = (lr&3)*100 + mt*4 + (lr>>2).
  bf16x8 frag[4][4];                         // [i][ks]
  #pragma unroll
  for (int i = 0; i < 4; ++i) {
    const int mt = wave + 8 * i;
    const int orow = (lr & 3) * 100 + mt * 4 + (lr >> 2);
    #pragma unroll
    for (int ks = 0; ks < 4; ++ks) {
      bf16x8 f;
      #pragma unroll
      for (int u = 0; u < 8; ++u) {
        float v = 0.f;
        const int k = ks * 32 + kg * 8 + u;
        if (mt < 25 && k < 100) v = whh[(long)orow * 100 + k];
        f[u] = (__bf16)bf2f(f2bf(v));
      }
      frag[i][ks] = f;
    }
  }

  // ---- init both h buffers to 0 (pad rows [100,128) stay 0 forever)
  for (int idx = tid; idx < 2 * 16 * 136; idx += 512) ((u16*)hB)[idx] = 0;

  float cc[4] = {0.f, 0.f, 0.f, 0.f};
  const bool bwd = (dir & 1);
  u16* se = ((dir < 2) ? s1e : s2e) + (bwd ? 100 : 0);
  const float* xb = xprojT + (long)dir * 128 * 400 * 32 + bh * 16 + lr;

  // xp = step t, xn = t+1, prefetch 2 deep
  float xp[4][4], xn[4][4];
  {
    const int t0 = bwd ? 127 : 0;
    const int t1 = bwd ? 126 : 1;
    #pragma unroll
    for (int i = 0; i < 4; ++i) {
      const int mt = wave + 8 * i;
      #pragma unroll
      for (int r = 0; r < 4; ++r) {
        const int row = r * 100 + mt * 4 + kg;   // orig n of gate r, unit j
        xp[i][r] = (mt < 25) ? xb[((long)t0 * 400 + row) * 32] : 0.f;
        xn[i][r] = (mt < 25) ? xb[((long)t1 * 400 + row) * 32] : 0.f;
      }
    }
  }
  __syncthreads();

  int cur = 0;
  for (int t = 0; t < 128; ++t) {
    const int ta = bwd ? (127 - t) : t;
    // issue prefetch for t+2 FIRST (2-step cover of HBM/L2 latency)
    float x2[4][4];
    if (t + 2 < 128) {
      const int t2 = bwd ? (125 - t) : (t + 2);
      #pragma unroll
      for (int i = 0; i < 4; ++i) {
        const int mt = wave + 8 * i;
        #pragma unroll
        for (int r = 0; r < 4; ++r) {
          const int row = r * 100 + mt * 4 + kg;
          x2[i][r] = (mt < 25) ? xb[((long)t2 * 400 + row) * 32] : 0.f;
        }
      }
    }
    // B-fragments from h (shared across m-tiles)
    bf16x8 hb[4];
    #pragma unroll
    for (int ks = 0; ks < 4; ++ks)
      hb[ks] = *(const bf16x8*)&hB[cur][lr][ks * 32 + kg * 8];
    // MFMA + in-register gates
    #pragma unroll
    for (int i = 0; i < 4; ++i) {
      const int mt = wave + 8 * i;
      if (mt < 25) {
        f32x4 a = {xp[i][0], xp[i][1], xp[i][2], xp[i][3]};
        #pragma unroll
        for (int ks = 0; ks < 4; ++ks)
          a = __builtin_amdgcn_mfma_f32_16x16x32_bf16(frag[i][ks], hb[ks], a, 0, 0, 0);
        // a[0]=i, a[1]=f, a[2]=g, a[3]=o for (j = mt*4+kg, b = lr)
        cc[i] = sigf(a[1]) * cc[i] + sigf(a[0]) * tanhfast(a[2]);
        const float h = sigf(a[3]) * tanhfast(cc[i]);
        const u16 h16 = f2bf(h);
        const int j = mt * 4 + kg;
        hB[cur ^ 1][lr][j] = h16;
        se[((long)(bh * 16 + lr) * 128 + ta) * 200 + j] = h16;
      }
    }
    // rotate prefetch regs (vmcnt wait for xn/x2 lands in copies below)
    #pragma unroll
    for (int i = 0; i < 4; ++i)
      #pragma unroll
      for (int r = 0; r < 4; ++r) { xp[i][r] = xn[i][r]; xn[i][r] = x2[i][r]; }
    wg_barrier();                            // h(nxt) visible; loads in flight
    cur ^= 1;
  }
}

// ---------------------------------------------------------------------------
// K3: reciprocal norms rn[sent][b][l][w*20+p] = 1/max(||bf16(s_d*W_pd)||, 1e-8)
// ---------------------------------------------------------------------------
__global__ __launch_bounds__(256) void k3_norms(
    const u16* __restrict__ s1e, const u16* __restrict__ s2e,
    const float* __restrict__ W1, const float* __restrict__ W2,
    float* __restrict__ rn)
{
  const int b = blockIdx.x, lc = blockIdx.y, sent = blockIdx.z;
  const u16* se = sent ? s2e : s1e;
  #pragma unroll
  for (int it = 0; it < 5; ++it) {
    const int idx = it * 256 + (int)threadIdx.x;  // < 1280
    const int l = lc * 32 + idx / 40;
    const int pw = idx % 40;
    const float* Wp = (pw < 20) ? (W1 + pw * 200) : (W2 + (pw - 20) * 200);
    const u16* srow = se + ((long)b * 128 + l) * 200;
    float acc = 0.f;
    #pragma unroll 10
    for (int q = 0; q < 50; ++q) {
      const u16x4 sv = *(const u16x4*)(srow + q * 4);
      const f32x4 wv = *(const f32x4*)(Wp + q * 4);
      #pragma unroll
      for (int u = 0; u < 4; ++u) {
        const float pr = bf2f(f2bf(bf2f(sv[u]) * wv[u]));
        acc += pr * pr;
      }
    }
    rn[(((long)sent * 32 + b) * 128 + l) * 40 + pw] = 1.f / fmaxf(sqrtf(acc), 1e-8f);
  }
}

// ---------------------------------------------------------------------------
// K4: matching. Per (b,p,w): C = (s1.Wp)(s2.Wp)^T via 16x16x32 bf16 MFMA,
//     scale by rnu_i*rnv_j, rowmax -> s1{f,b}, colmax -> s2{f,b}.
// ---------------------------------------------------------------------------
#define LDSS 232
__global__ __launch_bounds__(256, 1) void k4_match(
    const u16* __restrict__ s1e, const u16* __restrict__ s2e,
    const float* __restrict__ W1, const float* __restrict__ W2,
    const float* __restrict__ rn, float* __restrict__ out)
{
  __shared__ __align__(16) u16 aLb[128 * LDSS];
  __shared__ __align__(16) u16 bLb[128 * LDSS];
  __shared__ float rnuL[128], rnvL[128];
  __shared__ float redA[2][128], redB[2][128];
  const int b = blockIdx.x, p = blockIdx.y, w = blockIdx.z;
  const int tid = threadIdx.x;
  const float* Wp = (w ? W2 : W1) + p * 200;
  const u16* s1r = s1e + (long)b * 128 * 200;
  const u16* s2r = s2e + (long)b * 128 * 200;

  for (int idx = tid; idx < 128 * 56; idx += 256) {
    const int row = idx / 56;
    const int k = (idx % 56) * 4;
    u16x4 oa = {0, 0, 0, 0}, ob = {0, 0, 0, 0};
    if (k < 200) {
      const u16x4 sa = *(const u16x4*)(s1r + row * 200 + k);
      const u16x4 sb = *(const u16x4*)(s2r + row * 200 + k);
      const f32x4 wv = *(const f32x4*)(Wp + k);
      #pragma unroll
      for (int u = 0; u < 4; ++u) {
        oa[u] = f2bf(bf2f(sa[u]) * wv[u]);
        ob[u] = f2bf(bf2f(sb[u]) * wv[u]);
      }
    }
    *(u16x4*)(aLb + row * LDSS + k) = oa;
    *(u16x4*)(bLb + row * LDSS + k) = ob;
  }
  if (tid < 128) {
    const int pw = w * 20 + p;
    rnuL[tid] = rn[(((long)0 * 32 + b) * 128 + tid) * 40 + pw];
    rnvL[tid] = rn[(((long)1 * 32 + b) * 128 + tid) * 40 + pw];
  }
  __syncthreads();

  const int lane = tid & 63, wvid = tid >> 6;
  const int wr = wvid >> 1, wc = wvid & 1;
  const int lr = lane & 15, kg = lane >> 4;
  f32x4 acc[4][4];
  #pragma unroll
  for (int mt = 0; mt < 4; ++mt)
    #pragma unroll
    for (int nt = 0; nt < 4; ++nt) acc[mt][nt] = 0.f;

  const u16* a0 = aLb + (64 * wr + lr) * LDSS + kg * 8;
  const u16* b0 = bLb + (64 * wc + lr) * LDSS + kg * 8;
  #pragma unroll
  for (int ks = 0; ks < 7; ++ks) {
    bf16x8 af[4], bfv[4];
    #pragma unroll
    for (int mt = 0; mt < 4; ++mt) af[mt] = *(const bf16x8*)(a0 + mt * 16 * LDSS + ks * 32);
    #pragma unroll
    for (int nt = 0; nt < 4; ++nt) bfv[nt] = *(const bf16x8*)(b0 + nt * 16 * LDSS + ks * 32);
    #pragma unroll
    for (int mt = 0; mt < 4; ++mt)
      #pragma unroll
      for (int nt = 0; nt < 4; ++nt)
        acc[mt][nt] = __builtin_amdgcn_mfma_f32_16x16x32_bf16(af[mt], bfv[nt], acc[mt][nt], 0, 0, 0);
  }

  float ru[4][4], rm[4][4], rv[4], cm[4];
  #pragma unroll
  for (int mt = 0; mt < 4; ++mt)
    #pragma unroll
    for (int r = 0; r < 4; ++r) {
      ru[mt][r] = rnuL[64 * wr + mt * 16 + kg * 4 + r];
      rm[mt][r] = -3.0e38f;
    }
  #pragma unroll
  for (int nt = 0; nt < 4; ++nt) { rv[nt] = rnvL[64 * wc + nt * 16 + lr]; cm[nt] = -3.0e38f; }
  #pragma unroll
  for (int mt = 0; mt < 4; ++mt)
    #pragma unroll
    for (int nt = 0; nt < 4; ++nt)
      #pragma unroll
      for (int r = 0; r < 4; ++r) {
        const float v = acc[mt][nt][r] * ru[mt][r] * rv[nt];
        rm[mt][r] = fmaxf(rm[mt][r], v);
        cm[nt] = fmaxf(cm[nt], v);
      }
  #pragma unroll
  for (int mt = 0; mt < 4; ++mt)
    #pragma unroll
    for (int r = 0; r < 4; ++r) {
      float v = rm[mt][r];
      v = fmaxf(v, __shfl_xor(v, 1, 64));
      v = fmaxf(v, __shfl_xor(v, 2, 64));
      v = fmaxf(v, __shfl_xor(v, 4, 64));
      v = fmaxf(v, __shfl_xor(v, 8, 64));
      rm[mt][r] = v;
    }
  #pragma unroll
  for (int nt = 0; nt < 4; ++nt) {
    float v = cm[nt];
    v = fmaxf(v, __shfl_xor(v, 16, 64));
    v = fmaxf(v, __shfl_xor(v, 32, 64));
    cm[nt] = v;
  }
  if (lr == 0) {
    #pragma unroll
    for (int mt = 0; mt < 4; ++mt)
      #pragma unroll
      for (int r = 0; r < 4; ++r) redA[wc][64 * wr + mt * 16 + kg * 4 + r] = rm[mt][r];
  }
  if (kg == 0) {
    #pragma unroll
    for (int nt = 0; nt < 4; ++nt) redB[wr][64 * wc + nt * 16 + lr] = cm[nt];
  }
  __syncthreads();
  if (tid < 128) {
    const float o1 = fmaxf(redA[0][tid], redA[1][tid]);
    const float o2 = fmaxf(redB[0][tid], redB[1][tid]);
    const long oi = ((long)b * 128 + tid) * 20 + p;
    out[(long)w * 81920 + oi] = o1;
    out[163840 + (long)w * 81920 + oi] = o2;
  }
}

// ---------------------------------------------------------------------------
extern "C" void kernel_launch(void* const* d_in, const int* in_sizes, int n_in,
                              void* d_out, int out_size, void* d_ws, size_t ws_size,
                              hipStream_t stream) {
  const int* tok1 = (const int*)d_in[0];
  const int* tok2 = (const int*)d_in[1];
  const float* embed = (const float*)d_in[2];
  const float* wih0 = (const float*)d_in[3];
  const float* whh0 = (const float*)d_in[4];
  const float* bih0 = (const float*)d_in[5];
  const float* bhh0 = (const float*)d_in[6];
  const float* wih1 = (const float*)d_in[7];
  const float* whh1 = (const float*)d_in[8];
  const float* bih1 = (const float*)d_in[9];
  const float* bhh1 = (const float*)d_in[10];
  const float* wih2 = (const float*)d_in[11];
  const float* whh2 = (const float*)d_in[12];
  const float* bih2 = (const float*)d_in[13];
  const float* bhh2 = (const float*)d_in[14];
  const float* wih3 = (const float*)d_in[15];
  const float* whh3 = (const float*)d_in[16];
  const float* bih3 = (const float*)d_in[17];
  const float* bhh3 = (const float*)d_in[18];
  const float* W1 = (const float*)d_in[19];
  const float* W2 = (const float*)d_in[20];
  float* out = (float*)d_out;

  char* ws = (char*)d_ws;
  const size_t XPROJ_B = 26214400;   // 4*128*400*32*4  (xprojT)
  const size_t SE_B = 1638400;       // 32*128*200*2
  const size_t RN_B = 1310720;       // 2*32*128*40*4
  if (ws_size < XPROJ_B + 2 * SE_B + RN_B) return;
  float* xprojT = (float*)ws;
  u16* s1e = (u16*)(ws + XPROJ_B);
  u16* s2e = (u16*)(ws + XPROJ_B + SE_B);
  float* rn = (float*)(ws + XPROJ_B + 2 * SE_B);

  k1_xproj<<<dim3(32, 4), 256, 0, stream>>>(
      tok1, tok2, embed, wih0, wih1, wih2, wih3,
      bih0, bih1, bih2, bih3, bhh0, bhh1, bhh2, bhh3, xprojT);
  k2_lstm<<<dim3(2, 4), 512, 0, stream>>>(xprojT, whh0, whh1, whh2, whh3, s1e, s2e);
  k3_norms<<<dim3(32, 4, 2), 256, 0, stream>>>(s1e, s2e, W1, W2, rn);
  k4_match<<<dim3(32, 20, 2), 256, 0, stream>>>(s1e, s2e, W1, W2, rn, out);
}

// Round 6
// 406.014 us; speedup vs baseline: 1.1135x; 1.1135x over previous
//
#include <hip/hip_runtime.h>
#include <cstddef>

typedef float f32x4 __attribute__((ext_vector_type(4)));
typedef __bf16 bf16x8 __attribute__((ext_vector_type(8)));
typedef unsigned short u16;
typedef unsigned short u16x4 __attribute__((ext_vector_type(4)));

__device__ __forceinline__ u16 f2bf(float f) {
  unsigned u = __builtin_bit_cast(unsigned, f);
  u += 0x7FFFu + ((u >> 16) & 1u);   // RNE round to bf16
  return (u16)(u >> 16);
}
__device__ __forceinline__ float bf2f(u16 b) {
  unsigned u = ((unsigned)b) << 16;
  return __builtin_bit_cast(float, u);
}
__device__ __forceinline__ float sigf(float x) { return 1.0f / (1.0f + __expf(-x)); }
__device__ __forceinline__ float tanhfast(float x) { return 1.0f - 2.0f / (__expf(2.0f * x) + 1.0f); }

// Raw barrier: LDS-only drain (lgkmcnt), NO vmcnt drain. sched_barrier(0)
// stops post-barrier code hoisting (rule #18).
__device__ __forceinline__ void wg_barrier() {
  asm volatile("s_waitcnt lgkmcnt(0)" ::: "memory");
  __builtin_amdgcn_s_barrier();
  __builtin_amdgcn_sched_barrier(0);
}

// ---------------------------------------------------------------------------
// K1: xprojT[dir][l][n][b] = e(tok[b][l]) . wih[dir][n][:] + bih[n] + bhh[n]
// ---------------------------------------------------------------------------
#define K1_LDA 328
__global__ __launch_bounds__(256) void k1_xproj(
    const int* __restrict__ tok1, const int* __restrict__ tok2,
    const float* __restrict__ embed,
    const float* __restrict__ wihA, const float* __restrict__ wihB,
    const float* __restrict__ wihC, const float* __restrict__ wihD,
    const float* __restrict__ bihA, const float* __restrict__ bihB,
    const float* __restrict__ bihC, const float* __restrict__ bihD,
    const float* __restrict__ bhhA, const float* __restrict__ bhhB,
    const float* __restrict__ bhhC, const float* __restrict__ bhhD,
    float* __restrict__ xprojT)
{
  __shared__ __align__(16) u16 aL[128 * K1_LDA];
  __shared__ __align__(16) u16 bL[64 * K1_LDA];
  const int dir = blockIdx.y;
  const float* wih = (dir == 0) ? wihA : (dir == 1) ? wihB : (dir == 2) ? wihC : wihD;
  const float* bih = (dir == 0) ? bihA : (dir == 1) ? bihB : (dir == 2) ? bihC : bihD;
  const float* bhh = (dir == 0) ? bhhA : (dir == 1) ? bhhB : (dir == 2) ? bhhC : bhhD;
  const int* tok = (dir < 2) ? tok1 : tok2;
  const int lb = blockIdx.x * 4;
  const int tid = threadIdx.x;

  #pragma unroll
  for (int it = 0; it < 40; ++it) {
    const int idx = it * 256 + tid;
    const int row = idx / 80, k = (idx % 80) * 4;
    u16x4 o = {0, 0, 0, 0};
    if (k < 300) {
      const int bb = row & 31, ll = lb + (row >> 5);
      const long ar = (long)tok[bb * 128 + ll] * 300;
      const f32x4 v = *(const f32x4*)(embed + ar + k);
      o[0] = f2bf(v[0]); o[1] = f2bf(v[1]); o[2] = f2bf(v[2]); o[3] = f2bf(v[3]);
    }
    *(u16x4*)(aL + row * K1_LDA + k) = o;
  }

  const int lane = tid & 63, w = tid >> 6;
  const int lr = lane & 15, kg = lane >> 4;
  const u16* a0 = aL + (w * 32 + lr) * K1_LDA + kg * 8;
  const u16* b0 = bL + lr * K1_LDA + kg * 8;
  const int l = lb + w;

  for (int nc = 0; nc < 7; ++nc) {
    __syncthreads();
    #pragma unroll
    for (int it = 0; it < 20; ++it) {
      const int idx = it * 256 + tid;
      const int row = idx / 80, k = (idx % 80) * 4;
      const int n = nc * 64 + row;
      u16x4 o = {0, 0, 0, 0};
      if (k < 300 && n < 400) {
        const f32x4 v = *(const f32x4*)(wih + (long)n * 300 + k);
        o[0] = f2bf(v[0]); o[1] = f2bf(v[1]); o[2] = f2bf(v[2]); o[3] = f2bf(v[3]);
      }
      *(u16x4*)(bL + row * K1_LDA + k) = o;
    }
    __syncthreads();

    f32x4 acc[2][4];
    #pragma unroll
    for (int mt = 0; mt < 2; ++mt)
      #pragma unroll
      for (int nt = 0; nt < 4; ++nt) acc[mt][nt] = 0.f;
    #pragma unroll
    for (int ks = 0; ks < 10; ++ks) {
      bf16x8 af[2], bfv[4];
      #pragma unroll
      for (int mt = 0; mt < 2; ++mt) af[mt] = *(const bf16x8*)(a0 + mt * 16 * K1_LDA + ks * 32);
      #pragma unroll
      for (int nt = 0; nt < 4; ++nt) bfv[nt] = *(const bf16x8*)(b0 + nt * 16 * K1_LDA + ks * 32);
      #pragma unroll
      for (int mt = 0; mt < 2; ++mt)
        #pragma unroll
        for (int nt = 0; nt < 4; ++nt)
          acc[mt][nt] = __builtin_amdgcn_mfma_f32_16x16x32_bf16(af[mt], bfv[nt], acc[mt][nt], 0, 0, 0);
    }
    #pragma unroll
    for (int nt = 0; nt < 4; ++nt) {
      const int n = nc * 64 + nt * 16 + lr;
      if (n < 400) {
        const float bias = bih[n] + bhh[n];
        #pragma unroll
        for (int mt = 0; mt < 2; ++mt) {
          const int b0i = mt * 16 + kg * 4;
          f32x4 o;
          #pragma unroll
          for (int r = 0; r < 4; ++r) o[r] = acc[mt][nt][r] + bias;
          *(f32x4*)(xprojT + (((long)dir * 128 + l) * 400 + n) * 32 + b0i) = o;
        }
      }
    }
  }
}

// ---------------------------------------------------------------------------
// K2: recurrent LSTM, batched MFMA, gate-interleaved whh rows.
//   whh A-frags in NAMED register variables (f00..f33) -> no spill.
//   Unroll-by-2 time loop: even step reads hB[0]/writes hB[1] with xpA,
//   odd step the reverse with xpB. Prefetch issued after consumption,
//   consumed 2 steps later -> vmcnt never drained at the barrier.
// ---------------------------------------------------------------------------
__device__ __forceinline__ bf16x8 frag_ld(const float* __restrict__ whh,
                                          int mt, int ks, int lr, int kg) {
  bf16x8 f;
  const int orow = (lr & 3) * 100 + mt * 4 + (lr >> 2);
  #pragma unroll
  for (int u = 0; u < 8; ++u) {
    const int k = ks * 32 + kg * 8 + u;
    const float v = (mt < 25 && k < 100) ? whh[(long)orow * 100 + k] : 0.f;
    f[u] = (__bf16)bf2f(f2bf(v));
  }
  return f;
}

#define K2_MFMA(A_, F0_, F1_, F2_, F3_)                                     \
  A_ = __builtin_amdgcn_mfma_f32_16x16x32_bf16(F0_, hb0, A_, 0, 0, 0);      \
  A_ = __builtin_amdgcn_mfma_f32_16x16x32_bf16(F1_, hb1, A_, 0, 0, 0);      \
  A_ = __builtin_amdgcn_mfma_f32_16x16x32_bf16(F2_, hb2, A_, 0, 0, 0);      \
  A_ = __builtin_amdgcn_mfma_f32_16x16x32_bf16(F3_, hb3, A_, 0, 0, 0);

#define K2_GATES(A_, CC_, MT_, CUR_)                                        \
  if ((MT_) < 25) {                                                         \
    CC_ = sigf(A_[1]) * CC_ + sigf(A_[0]) * tanhfast(A_[2]);                \
    const float h_ = sigf(A_[3]) * tanhfast(CC_);                           \
    const u16 h16_ = f2bf(h_);                                              \
    const int j_ = (MT_) * 4 + kg;                                          \
    hB[(CUR_) ^ 1][lr][j_] = h16_;                                          \
    se[((long)(bh * 16 + lr) * 128 + ta_) * 200 + j_] = h16_;               \
  }

#define K2_STEP(T_, CUR_, XPv)                                              \
  {                                                                         \
    const int ta_ = bwd ? (127 - (T_)) : (T_);                              \
    bf16x8 hb0 = *(const bf16x8*)&hB[CUR_][lr][kg * 8];                     \
    bf16x8 hb1 = *(const bf16x8*)&hB[CUR_][lr][32 + kg * 8];                \
    bf16x8 hb2 = *(const bf16x8*)&hB[CUR_][lr][64 + kg * 8];                \
    bf16x8 hb3 = *(const bf16x8*)&hB[CUR_][lr][96 + kg * 8];                \
    f32x4 a0 = {XPv[0], XPv[1], XPv[2], XPv[3]};                            \
    f32x4 a1 = {XPv[4], XPv[5], XPv[6], XPv[7]};                            \
    f32x4 a2 = {XPv[8], XPv[9], XPv[10], XPv[11]};                          \
    f32x4 a3 = {XPv[12], XPv[13], XPv[14], XPv[15]};                        \
    if ((T_) + 2 < 128) {  /* prefetch into XPv for t+2 */                  \
      const int t2_ = bwd ? (125 - (T_)) : ((T_) + 2);                      \
      _Pragma("unroll")                                                     \
      for (int i_ = 0; i_ < 4; ++i_) {                                      \
        const int mt_ = wave + 8 * i_;                                      \
        _Pragma("unroll")                                                   \
        for (int r_ = 0; r_ < 4; ++r_)                                      \
          XPv[i_ * 4 + r_] = (mt_ < 25)                                     \
            ? xb[((long)t2_ * 400 + r_ * 100 + mt_ * 4 + kg) * 32] : 0.f;   \
      }                                                                     \
    }                                                                       \
    K2_MFMA(a0, f00, f01, f02, f03)                                         \
    K2_MFMA(a1, f10, f11, f12, f13)                                         \
    K2_MFMA(a2, f20, f21, f22, f23)                                         \
    if (mt3 < 25) { K2_MFMA(a3, f30, f31, f32, f33) }                       \
    K2_GATES(a0, cc0, mt0, CUR_)                                            \
    K2_GATES(a1, cc1, mt1, CUR_)                                            \
    K2_GATES(a2, cc2, mt2, CUR_)                                            \
    K2_GATES(a3, cc3, mt3, CUR_)                                            \
  }

__global__ __launch_bounds__(512, 1) void k2_lstm(
    const float* __restrict__ xprojT,
    const float* __restrict__ whhA, const float* __restrict__ whhB,
    const float* __restrict__ whhC, const float* __restrict__ whhD,
    u16* __restrict__ s1e, u16* __restrict__ s2e)
{
  const int bh = blockIdx.x;                 // batch half
  const int dir = blockIdx.y;
  const float* whh = (dir == 0) ? whhA : (dir == 1) ? whhB : (dir == 2) ? whhC : whhD;
  const int tid = threadIdx.x;
  const int lane = tid & 63, wave = tid >> 6;
  const int lr = lane & 15, kg = lane >> 4;
  const int mt0 = wave, mt1 = wave + 8, mt2 = wave + 16, mt3 = wave + 24;

  __shared__ __align__(16) u16 hB[2][16][136];

  // whh A-fragments in named registers (one-time gather)
  bf16x8 f00 = frag_ld(whh, mt0, 0, lr, kg), f01 = frag_ld(whh, mt0, 1, lr, kg),
         f02 = frag_ld(whh, mt0, 2, lr, kg), f03 = frag_ld(whh, mt0, 3, lr, kg);
  bf16x8 f10 = frag_ld(whh, mt1, 0, lr, kg), f11 = frag_ld(whh, mt1, 1, lr, kg),
         f12 = frag_ld(whh, mt1, 2, lr, kg), f13 = frag_ld(whh, mt1, 3, lr, kg);
  bf16x8 f20 = frag_ld(whh, mt2, 0, lr, kg), f21 = frag_ld(whh, mt2, 1, lr, kg),
         f22 = frag_ld(whh, mt2, 2, lr, kg), f23 = frag_ld(whh, mt2, 3, lr, kg);
  bf16x8 f30 = frag_ld(whh, mt3, 0, lr, kg), f31 = frag_ld(whh, mt3, 1, lr, kg),
         f32 = frag_ld(whh, mt3, 2, lr, kg), f33 = frag_ld(whh, mt3, 3, lr, kg);

  for (int idx = tid; idx < 2 * 16 * 136; idx += 512) ((u16*)hB)[idx] = 0;

  float cc0 = 0.f, cc1 = 0.f, cc2 = 0.f, cc3 = 0.f;
  const bool bwd = (dir & 1);
  u16* se = ((dir < 2) ? s1e : s2e) + (bwd ? 100 : 0);
  const float* xb = xprojT + (long)dir * 128 * 400 * 32 + bh * 16 + lr;

  float xpA[16], xpB[16];
  {
    const int t0 = bwd ? 127 : 0, t1 = bwd ? 126 : 1;
    #pragma unroll
    for (int i = 0; i < 4; ++i) {
      const int mt = wave + 8 * i;
      #pragma unroll
      for (int r = 0; r < 4; ++r) {
        xpA[i * 4 + r] = (mt < 25) ? xb[((long)t0 * 400 + r * 100 + mt * 4 + kg) * 32] : 0.f;
        xpB[i * 4 + r] = (mt < 25) ? xb[((long)t1 * 400 + r * 100 + mt * 4 + kg) * 32] : 0.f;
      }
    }
  }
  __syncthreads();

  #pragma unroll 1
  for (int tt = 0; tt < 64; ++tt) {
    K2_STEP(2 * tt, 0, xpA)      // reads hB[0], writes hB[1]
    wg_barrier();
    K2_STEP(2 * tt + 1, 1, xpB)  // reads hB[1], writes hB[0]
    wg_barrier();
  }
}

// ---------------------------------------------------------------------------
// K3: reciprocal norms rn[sent][b][l][w*20+p] = 1/max(||bf16(s_d*W_pd)||, 1e-8)
// ---------------------------------------------------------------------------
__global__ __launch_bounds__(256) void k3_norms(
    const u16* __restrict__ s1e, const u16* __restrict__ s2e,
    const float* __restrict__ W1, const float* __restrict__ W2,
    float* __restrict__ rn)
{
  const int b = blockIdx.x, lc = blockIdx.y, sent = blockIdx.z;
  const u16* se = sent ? s2e : s1e;
  #pragma unroll
  for (int it = 0; it < 5; ++it) {
    const int idx = it * 256 + (int)threadIdx.x;
    const int l = lc * 32 + idx / 40;
    const int pw = idx % 40;
    const float* Wp = (pw < 20) ? (W1 + pw * 200) : (W2 + (pw - 20) * 200);
    const u16* srow = se + ((long)b * 128 + l) * 200;
    float acc = 0.f;
    #pragma unroll 10
    for (int q = 0; q < 50; ++q) {
      const u16x4 sv = *(const u16x4*)(srow + q * 4);
      const f32x4 wv = *(const f32x4*)(Wp + q * 4);
      #pragma unroll
      for (int u = 0; u < 4; ++u) {
        const float pr = bf2f(f2bf(bf2f(sv[u]) * wv[u]));
        acc += pr * pr;
      }
    }
    rn[(((long)sent * 32 + b) * 128 + l) * 40 + pw] = 1.f / fmaxf(sqrtf(acc), 1e-8f);
  }
}

// ---------------------------------------------------------------------------
// K4: matching. Per (b,p,w): C = (s1.Wp)(s2.Wp)^T via 16x16x32 bf16 MFMA,
//     scale by rnu_i*rnv_j, rowmax -> s1{f,b}, colmax -> s2{f,b}.
// ---------------------------------------------------------------------------
#define LDSS 232
__global__ __launch_bounds__(256, 1) void k4_match(
    const u16* __restrict__ s1e, const u16* __restrict__ s2e,
    const float* __restrict__ W1, const float* __restrict__ W2,
    const float* __restrict__ rn, float* __restrict__ out)
{
  __shared__ __align__(16) u16 aLb[128 * LDSS];
  __shared__ __align__(16) u16 bLb[128 * LDSS];
  __shared__ float rnuL[128], rnvL[128];
  __shared__ float redA[2][128], redB[2][128];
  const int b = blockIdx.x, p = blockIdx.y, w = blockIdx.z;
  const int tid = threadIdx.x;
  const float* Wp = (w ? W2 : W1) + p * 200;
  const u16* s1r = s1e + (long)b * 128 * 200;
  const u16* s2r = s2e + (long)b * 128 * 200;

  for (int idx = tid; idx < 128 * 56; idx += 256) {
    const int row = idx / 56;
    const int k = (idx % 56) * 4;
    u16x4 oa = {0, 0, 0, 0}, ob = {0, 0, 0, 0};
    if (k < 200) {
      const u16x4 sa = *(const u16x4*)(s1r + row * 200 + k);
      const u16x4 sb = *(const u16x4*)(s2r + row * 200 + k);
      const f32x4 wv = *(const f32x4*)(Wp + k);
      #pragma unroll
      for (int u = 0; u < 4; ++u) {
        oa[u] = f2bf(bf2f(sa[u]) * wv[u]);
        ob[u] = f2bf(bf2f(sb[u]) * wv[u]);
      }
    }
    *(u16x4*)(aLb + row * LDSS + k) = oa;
    *(u16x4*)(bLb + row * LDSS + k) = ob;
  }
  if (tid < 128) {
    const int pw = w * 20 + p;
    rnuL[tid] = rn[(((long)0 * 32 + b) * 128 + tid) * 40 + pw];
    rnvL[tid] = rn[(((long)1 * 32 + b) * 128 + tid) * 40 + pw];
  }
  __syncthreads();

  const int lane = tid & 63, wvid = tid >> 6;
  const int wr = wvid >> 1, wc = wvid & 1;
  const int lr = lane & 15, kg = lane >> 4;
  f32x4 acc[4][4];
  #pragma unroll
  for (int mt = 0; mt < 4; ++mt)
    #pragma unroll
    for (int nt = 0; nt < 4; ++nt) acc[mt][nt] = 0.f;

  const u16* a0 = aLb + (64 * wr + lr) * LDSS + kg * 8;
  const u16* b0 = bLb + (64 * wc + lr) * LDSS + kg * 8;
  #pragma unroll
  for (int ks = 0; ks < 7; ++ks) {
    bf16x8 af[4], bfv[4];
    #pragma unroll
    for (int mt = 0; mt < 4; ++mt) af[mt] = *(const bf16x8*)(a0 + mt * 16 * LDSS + ks * 32);
    #pragma unroll
    for (int nt = 0; nt < 4; ++nt) bfv[nt] = *(const bf16x8*)(b0 + nt * 16 * LDSS + ks * 32);
    #pragma unroll
    for (int mt = 0; mt < 4; ++mt)
      #pragma unroll
      for (int nt = 0; nt < 4; ++nt)
        acc[mt][nt] = __builtin_amdgcn_mfma_f32_16x16x32_bf16(af[mt], bfv[nt], acc[mt][nt], 0, 0, 0);
  }

  float ru[4][4], rm[4][4], rv[4], cm[4];
  #pragma unroll
  for (int mt = 0; mt < 4; ++mt)
    #pragma unroll
    for (int r = 0; r < 4; ++r) {
      ru[mt][r] = rnuL[64 * wr + mt * 16 + kg * 4 + r];
      rm[mt][r] = -3.0e38f;
    }
  #pragma unroll
  for (int nt = 0; nt < 4; ++nt) { rv[nt] = rnvL[64 * wc + nt * 16 + lr]; cm[nt] = -3.0e38f; }
  #pragma unroll
  for (int mt = 0; mt < 4; ++mt)
    #pragma unroll
    for (int nt = 0; nt < 4; ++nt)
      #pragma unroll
      for (int r = 0; r < 4; ++r) {
        const float v = acc[mt][nt][r] * ru[mt][r] * rv[nt];
        rm[mt][r] = fmaxf(rm[mt][r], v);
        cm[nt] = fmaxf(cm[nt], v);
      }
  #pragma unroll
  for (int mt = 0; mt < 4; ++mt)
    #pragma unroll
    for (int r = 0; r < 4; ++r) {
      float v = rm[mt][r];
      v = fmaxf(v, __shfl_xor(v, 1, 64));
      v = fmaxf(v, __shfl_xor(v, 2, 64));
      v = fmaxf(v, __shfl_xor(v, 4, 64));
      v = fmaxf(v, __shfl_xor(v, 8, 64));
      rm[mt][r] = v;
    }
  #pragma unroll
  for (int nt = 0; nt < 4; ++nt) {
    float v = cm[nt];
    v = fmaxf(v, __shfl_xor(v, 16, 64));
    v = fmaxf(v, __shfl_xor(v, 32, 64));
    cm[nt] = v;
  }
  if (lr == 0) {
    #pragma unroll
    for (int mt = 0; mt < 4; ++mt)
      #pragma unroll
      for (int r = 0; r < 4; ++r) redA[wc][64 * wr + mt * 16 + kg * 4 + r] = rm[mt][r];
  }
  if (kg == 0) {
    #pragma unroll
    for (int nt = 0; nt < 4; ++nt) redB[wr][64 * wc + nt * 16 + lr] = cm[nt];
  }
  __syncthreads();
  if (tid < 128) {
    const float o1 = fmaxf(redA[0][tid], redA[1][tid]);
    const float o2 = fmaxf(redB[0][tid], redB[1][tid]);
    const long oi = ((long)b * 128 + tid) * 20 + p;
    out[(long)w * 81920 + oi] = o1;
    out[163840 + (long)w * 81920 + oi] = o2;
  }
}

// ---------------------------------------------------------------------------
extern "C" void kernel_launch(void* const* d_in, const int* in_sizes, int n_in,
                              void* d_out, int out_size, void* d_ws, size_t ws_size,
                              hipStream_t stream) {
  const int* tok1 = (const int*)d_in[0];
  const int* tok2 = (const int*)d_in[1];
  const float* embed = (const float*)d_in[2];
  const float* wih0 = (const float*)d_in[3];
  const float* whh0 = (const float*)d_in[4];
  const float* bih0 = (const float*)d_in[5];
  const float* bhh0 = (const float*)d_in[6];
  const float* wih1 = (const float*)d_in[7];
  const float* whh1 = (const float*)d_in[8];
  const float* bih1 = (const float*)d_in[9];
  const float* bhh1 = (const float*)d_in[10];
  const float* wih2 = (const float*)d_in[11];
  const float* whh2 = (const float*)d_in[12];
  const float* bih2 = (const float*)d_in[13];
  const float* bhh2 = (const float*)d_in[14];
  const float* wih3 = (const float*)d_in[15];
  const float* whh3 = (const float*)d_in[16];
  const float* bih3 = (const float*)d_in[17];
  const float* bhh3 = (const float*)d_in[18];
  const float* W1 = (const float*)d_in[19];
  const float* W2 = (const float*)d_in[20];
  float* out = (float*)d_out;

  char* ws = (char*)d_ws;
  const size_t XPROJ_B = 26214400;   // 4*128*400*32*4  (xprojT)
  const size_t SE_B = 1638400;       // 32*128*200*2
  const size_t RN_B = 1310720;       // 2*32*128*40*4
  if (ws_size < XPROJ_B + 2 * SE_B + RN_B) return;
  float* xprojT = (float*)ws;
  u16* s1e = (u16*)(ws + XPROJ_B);
  u16* s2e = (u16*)(ws + XPROJ_B + SE_B);
  float* rn = (float*)(ws + XPROJ_B + 2 * SE_B);

  k1_xproj<<<dim3(32, 4), 256, 0, stream>>>(
      tok1, tok2, embed, wih0, wih1, wih2, wih3,
      bih0, bih1, bih2, bih3, bhh0, bhh1, bhh2, bhh3, xprojT);
  k2_lstm<<<dim3(2, 4), 512, 0, stream>>>(xprojT, whh0, whh1, whh2, whh3, s1e, s2e);
  k3_norms<<<dim3(32, 4, 2), 256, 0, stream>>>(s1e, s2e, W1, W2, rn);
  k4_match<<<dim3(32, 20, 2), 256, 0, stream>>>(s1e, s2e, W1, W2, rn, out);
}

// Round 8
// 391.899 us; speedup vs baseline: 1.1536x; 1.0360x over previous
//
#include <hip/hip_runtime.h>
#include <cstddef>

typedef float f32x4 __attribute__((ext_vector_type(4)));
typedef __bf16 bf16x8 __attribute__((ext_vector_type(8)));
typedef unsigned short u16;
typedef unsigned short u16x4 __attribute__((ext_vector_type(4)));

__device__ __forceinline__ u16 f2bf(float f) {
  unsigned u = __builtin_bit_cast(unsigned, f);
  u += 0x7FFFu + ((u >> 16) & 1u);   // RNE round to bf16
  return (u16)(u >> 16);
}
__device__ __forceinline__ float bf2f(u16 b) {
  unsigned u = ((unsigned)b) << 16;
  return __builtin_bit_cast(float, u);
}
__device__ __forceinline__ float sigf(float x) { return 1.0f / (1.0f + __expf(-x)); }
__device__ __forceinline__ float tanhfast(float x) { return 1.0f - 2.0f / (__expf(2.0f * x) + 1.0f); }

// Raw barrier: LDS-only drain (lgkmcnt), NO vmcnt drain. sched_barrier(0)
// stops post-barrier code hoisting (rule #18).
__device__ __forceinline__ void wg_barrier() {
  asm volatile("s_waitcnt lgkmcnt(0)" ::: "memory");
  __builtin_amdgcn_s_barrier();
  __builtin_amdgcn_sched_barrier(0);
}

// ---------------------------------------------------------------------------
// K1: xprojP[dir][l][j(100)][b(32)][r(4)] =
//       e(tok[b][l]) . wih[dir][n][:] + bih[n] + bhh[n],  n = r*100 + j
//   Layout chosen so k2's per-thread 16 step-floats are contiguous (4 dwordx4).
// ---------------------------------------------------------------------------
#define K1_LDA 328
__global__ __launch_bounds__(256) void k1_xproj(
    const int* __restrict__ tok1, const int* __restrict__ tok2,
    const float* __restrict__ embed,
    const float* __restrict__ wihA, const float* __restrict__ wihB,
    const float* __restrict__ wihC, const float* __restrict__ wihD,
    const float* __restrict__ bihA, const float* __restrict__ bihB,
    const float* __restrict__ bihC, const float* __restrict__ bihD,
    const float* __restrict__ bhhA, const float* __restrict__ bhhB,
    const float* __restrict__ bhhC, const float* __restrict__ bhhD,
    float* __restrict__ xprojP)
{
  __shared__ __align__(16) u16 aL[128 * K1_LDA];
  __shared__ __align__(16) u16 bL[64 * K1_LDA];
  const int dir = blockIdx.y;
  const float* wih = (dir == 0) ? wihA : (dir == 1) ? wihB : (dir == 2) ? wihC : wihD;
  const float* bih = (dir == 0) ? bihA : (dir == 1) ? bihB : (dir == 2) ? bihC : bihD;
  const float* bhh = (dir == 0) ? bhhA : (dir == 1) ? bhhB : (dir == 2) ? bhhC : bhhD;
  const int* tok = (dir < 2) ? tok1 : tok2;
  const int lb = blockIdx.x * 4;
  const int tid = threadIdx.x;

  #pragma unroll
  for (int it = 0; it < 40; ++it) {            // A: 128 rows (l,b), K pad 320
    const int idx = it * 256 + tid;
    const int row = idx / 80, k = (idx % 80) * 4;
    u16x4 o = {0, 0, 0, 0};
    if (k < 300) {
      const int bb = row & 31, ll = lb + (row >> 5);
      const long ar = (long)tok[bb * 128 + ll] * 300;
      const f32x4 v = *(const f32x4*)(embed + ar + k);
      o[0] = f2bf(v[0]); o[1] = f2bf(v[1]); o[2] = f2bf(v[2]); o[3] = f2bf(v[3]);
    }
    *(u16x4*)(aL + row * K1_LDA + k) = o;
  }

  const int lane = tid & 63, w = tid >> 6;
  const int lr = lane & 15, kg = lane >> 4;
  const u16* a0 = aL + (w * 32 + lr) * K1_LDA + kg * 8;
  const u16* b0 = bL + lr * K1_LDA + kg * 8;
  const int l = lb + w;

  for (int nc = 0; nc < 7; ++nc) {
    __syncthreads();
    #pragma unroll
    for (int it = 0; it < 20; ++it) {          // B chunk: 64 n-rows
      const int idx = it * 256 + tid;
      const int row = idx / 80, k = (idx % 80) * 4;
      const int n = nc * 64 + row;
      u16x4 o = {0, 0, 0, 0};
      if (k < 300 && n < 400) {
        const f32x4 v = *(const f32x4*)(wih + (long)n * 300 + k);
        o[0] = f2bf(v[0]); o[1] = f2bf(v[1]); o[2] = f2bf(v[2]); o[3] = f2bf(v[3]);
      }
      *(u16x4*)(bL + row * K1_LDA + k) = o;
    }
    __syncthreads();

    f32x4 acc[2][4];
    #pragma unroll
    for (int mt = 0; mt < 2; ++mt)
      #pragma unroll
      for (int nt = 0; nt < 4; ++nt) acc[mt][nt] = 0.f;
    #pragma unroll
    for (int ks = 0; ks < 10; ++ks) {
      bf16x8 af[2], bfv[4];
      #pragma unroll
      for (int mt = 0; mt < 2; ++mt) af[mt] = *(const bf16x8*)(a0 + mt * 16 * K1_LDA + ks * 32);
      #pragma unroll
      for (int nt = 0; nt < 4; ++nt) bfv[nt] = *(const bf16x8*)(b0 + nt * 16 * K1_LDA + ks * 32);
      #pragma unroll
      for (int mt = 0; mt < 2; ++mt)
        #pragma unroll
        for (int nt = 0; nt < 4; ++nt)
          acc[mt][nt] = __builtin_amdgcn_mfma_f32_16x16x32_bf16(af[mt], bfv[nt], acc[mt][nt], 0, 0, 0);
    }
    // scatter-store into permuted layout (n -> r, j), b = mt*16+kg*4+rr
    #pragma unroll
    for (int nt = 0; nt < 4; ++nt) {
      const int n = nc * 64 + nt * 16 + lr;
      if (n < 400) {
        const float bias = bih[n] + bhh[n];
        const int r = (n * 41) >> 12;          // n/100 for n<400
        const int q = n - r * 100;             // j
        const long base = ((long)dir * 128 + l) * 12800 + (long)q * 128;
        #pragma unroll
        for (int mt = 0; mt < 2; ++mt)
          #pragma unroll
          for (int rr = 0; rr < 4; ++rr) {
            const int b = mt * 16 + kg * 4 + rr;
            xprojP[base + b * 4 + r] = acc[mt][nt][rr] + bias;
          }
      }
    }
  }
}

// ---------------------------------------------------------------------------
// K2: recurrent LSTM, batched MFMA, gate-interleaved whh rows.
//   - xprojP layout gives per-thread contiguous dwordx4 loads; addresses are
//     {uniform slab ptr advanced +-12800 floats/step} + {const thread offset}.
//   - hB [2][16][128] u16, XOR-swizzled 16B granules (g ^= row&7).
//   - gates in-register on MFMA accumulator; coalesced se via copy phase
//     (512 thr: 400 active x 2 dwords = 800 dwords = full 16x100 tile).
// ---------------------------------------------------------------------------
__device__ __forceinline__ bf16x8 frag_ld(const float* __restrict__ whh,
                                          int mt, int ks, int lr, int kg) {
  bf16x8 f;
  const int orow = (lr & 3) * 100 + mt * 4 + (lr >> 2);
  #pragma unroll
  for (int u = 0; u < 8; ++u) {
    const int k = ks * 32 + kg * 8 + u;
    const float v = (mt < 25 && k < 100) ? whh[(long)orow * 100 + k] : 0.f;
    f[u] = (__bf16)bf2f(f2bf(v));
  }
  return f;
}

#define K2_MFMA4(A_, F0_, F1_, F2_, F3_)                                    \
  A_ = __builtin_amdgcn_mfma_f32_16x16x32_bf16(F0_, hb0, A_, 0, 0, 0);      \
  A_ = __builtin_amdgcn_mfma_f32_16x16x32_bf16(F1_, hb1, A_, 0, 0, 0);      \
  A_ = __builtin_amdgcn_mfma_f32_16x16x32_bf16(F2_, hb2, A_, 0, 0, 0);      \
  A_ = __builtin_amdgcn_mfma_f32_16x16x32_bf16(F3_, hb3, A_, 0, 0, 0);

#define K2_GATE(A_, CC_, WRO_, WBUF_)                                       \
  {                                                                         \
    CC_ = sigf(A_[1]) * CC_ + sigf(A_[0]) * tanhfast(A_[2]);                \
    const float h_ = sigf(A_[3]) * tanhfast(CC_);                           \
    *(u16*)(hby + (WRO_) + (WBUF_) * 4096) = f2bf(h_);                      \
  }

// step T_: reads buf RB_, writes buf RB_^1; consumes XA*, prefetches t+2 into XA*
#define K2_STEP(RB_, XA0, XA1, XA2, XA3)                                    \
  {                                                                         \
    bf16x8 hb0 = *(const bf16x8*)(hby + rd0 + (RB_) * 4096);                \
    bf16x8 hb1 = *(const bf16x8*)(hby + rd1 + (RB_) * 4096);                \
    bf16x8 hb2 = *(const bf16x8*)(hby + rd2 + (RB_) * 4096);                \
    bf16x8 hb3 = *(const bf16x8*)(hby + rd3 + (RB_) * 4096);                \
    f32x4 a0 = XA0, a1 = XA1, a2 = XA2, a3 = XA3;                           \
    XA0 = *(const f32x4*)(pstep + off0);                                    \
    XA1 = *(const f32x4*)(pstep + off1);                                    \
    XA2 = *(const f32x4*)(pstep + off2);                                    \
    if (wave == 0) XA3 = *(const f32x4*)(pstep + off3);                     \
    pstep += dstep;                                                         \
    K2_MFMA4(a0, f00, f01, f02, f03)                                        \
    K2_MFMA4(a1, f10, f11, f12, f13)                                        \
    K2_MFMA4(a2, f20, f21, f22, f23)                                        \
    if (wave == 0) { K2_MFMA4(a3, f30, f31, f32, f33) }                     \
    K2_GATE(a0, cc0, wr0, (RB_) ^ 1)                                        \
    K2_GATE(a1, cc1, wr1, (RB_) ^ 1)                                        \
    K2_GATE(a2, cc2, wr2, (RB_) ^ 1)                                        \
    if (wave == 0) { K2_GATE(a3, cc3, wr3, (RB_) ^ 1) }                     \
  }

#define K2_COPY(TA_, CB_)                                                   \
  if (cact) {                                                               \
    const unsigned v_ = *(const unsigned*)(hby + cprd + (CB_) * 4096);      \
    const unsigned v2_ = *(const unsigned*)(hby + cprd + 2048 + (CB_) * 4096); \
    seD[cpbase + (TA_) * 100] = v_;                                         \
    seD[cpbase2 + (TA_) * 100] = v2_;                                       \
  }

__global__ __launch_bounds__(512, 1) void k2_lstm(
    const float* __restrict__ xprojP,
    const float* __restrict__ whhA, const float* __restrict__ whhB,
    const float* __restrict__ whhC, const float* __restrict__ whhD,
    u16* __restrict__ s1e, u16* __restrict__ s2e)
{
  const int bh = blockIdx.x;                 // batch half
  const int dir = blockIdx.y;
  const float* whh = (dir == 0) ? whhA : (dir == 1) ? whhB : (dir == 2) ? whhC : whhD;
  const int tid = threadIdx.x;
  const int lane = tid & 63, wave = tid >> 6;
  const int lr = lane & 15, kg = lane >> 4;
  const int mt0 = wave, mt1 = wave + 8, mt2 = wave + 16, mt3 = wave + 24;

  __shared__ __align__(16) u16 hraw[2 * 16 * 128];   // [buf][b=16][k=128], swizzled
  char* hby = (char*)hraw;

  // whh A-fragments in named registers (one-time gather)
  bf16x8 f00 = frag_ld(whh, mt0, 0, lr, kg), f01 = frag_ld(whh, mt0, 1, lr, kg),
         f02 = frag_ld(whh, mt0, 2, lr, kg), f03 = frag_ld(whh, mt0, 3, lr, kg);
  bf16x8 f10 = frag_ld(whh, mt1, 0, lr, kg), f11 = frag_ld(whh, mt1, 1, lr, kg),
         f12 = frag_ld(whh, mt1, 2, lr, kg), f13 = frag_ld(whh, mt1, 3, lr, kg);
  bf16x8 f20 = frag_ld(whh, mt2, 0, lr, kg), f21 = frag_ld(whh, mt2, 1, lr, kg),
         f22 = frag_ld(whh, mt2, 2, lr, kg), f23 = frag_ld(whh, mt2, 3, lr, kg);
  bf16x8 f30 = frag_ld(whh, mt3, 0, lr, kg), f31 = frag_ld(whh, mt3, 1, lr, kg),
         f32 = frag_ld(whh, mt3, 2, lr, kg), f33 = frag_ld(whh, mt3, 3, lr, kg);

  for (int idx = tid; idx < 2 * 16 * 128; idx += 512) hraw[idx] = 0;

  // LDS byte addresses (constant across steps; buf via +4096)
  const int e7 = lr & 7;
  const int rd0 = lr * 256 + ((kg ^ e7) * 16);
  const int rd1 = lr * 256 + (((4 + kg) ^ e7) * 16);
  const int rd2 = lr * 256 + (((8 + kg) ^ e7) * 16);
  const int rd3 = lr * 256 + (((12 + kg) ^ e7) * 16);
  const int wr0 = lr * 256 + (((mt0 >> 1) ^ e7) * 16) + ((mt0 & 1) * 4 + kg) * 2;
  const int wr1 = lr * 256 + (((mt1 >> 1) ^ e7) * 16) + ((mt1 & 1) * 4 + kg) * 2;
  const int wr2 = lr * 256 + (((mt2 >> 1) ^ e7) * 16) + ((mt2 & 1) * 4 + kg) * 2;
  const int wr3 = lr * 256 + (((mt3 >> 1) ^ e7) * 16) + ((mt3 & 1) * 4 + kg) * 2;

  // copy-phase setup: thread -> (b, j2) dword of the 16x100 h tile; 2 dwords
  // per thread (batches cb and cb+8; same XOR since (cb+8)&7 == cb for cb<8)
  const bool cact = (tid < 400);
  const int cb = tid / 50, cj2 = tid - cb * 50;
  const int cprd = cb * 256 + (((cj2 >> 2) ^ (cb & 7)) * 16) + (cj2 & 3) * 4;
  const bool bwd = (dir & 1);
  unsigned* seD = (unsigned*)((dir < 2) ? s1e : s2e);
  const long cpbase = ((long)(bh * 16 + cb) * 128) * 100 + (bwd ? 50 : 0) + cj2;
  const long cpbase2 = cpbase + (long)8 * 128 * 100;

  // xproj pointers: uniform slab ptr + constant per-thread offsets
  const float* pbase = xprojP + (long)dir * 128 * 12800;
  const int off0 = ((mt0 * 4 + kg) * 32 + bh * 16 + lr) * 4;
  const int off1 = ((mt1 * 4 + kg) * 32 + bh * 16 + lr) * 4;
  const int off2 = ((mt2 * 4 + kg) * 32 + bh * 16 + lr) * 4;
  const int off3 = ((mt3 * 4 + kg) * 32 + bh * 16 + lr) * 4;  // wave0 only
  const long dstep = bwd ? -12800 : 12800;
  const float* pstep = pbase + (long)(bwd ? 125 : 2) * 12800;

  f32x4 xa0, xa1, xa2, xa3, xb0, xb1, xb2, xb3;
  {
    const float* p0 = pbase + (long)(bwd ? 127 : 0) * 12800;
    const float* p1 = pbase + (long)(bwd ? 126 : 1) * 12800;
    xa0 = *(const f32x4*)(p0 + off0); xa1 = *(const f32x4*)(p0 + off1);
    xa2 = *(const f32x4*)(p0 + off2);
    xb0 = *(const f32x4*)(p1 + off0); xb1 = *(const f32x4*)(p1 + off1);
    xb2 = *(const f32x4*)(p1 + off2);
    xa3 = xb3 = f32x4{0.f, 0.f, 0.f, 0.f};
    if (wave == 0) { xa3 = *(const f32x4*)(p0 + off3); xb3 = *(const f32x4*)(p1 + off3); }
  }
  float cc0 = 0.f, cc1 = 0.f, cc2 = 0.f, cc3 = 0.f;
  __syncthreads();

  #pragma unroll 1
  for (int tt = 0; tt < 64; ++tt) {
    const int te = 2 * tt, to = 2 * tt + 1;
    K2_STEP(0, xa0, xa1, xa2, xa3)             // reads buf0, writes buf1
    wg_barrier();
    K2_COPY(bwd ? 127 - te : te, 1)
    K2_STEP(1, xb0, xb1, xb2, xb3)             // reads buf1, writes buf0
    wg_barrier();
    K2_COPY(bwd ? 127 - to : to, 0)
  }
}

// ---------------------------------------------------------------------------
// K3: reciprocal norms rn[sent][b][l][w*20+p] = 1/max(||bf16(s_d*W_pd)||, 1e-8)
// ---------------------------------------------------------------------------
__global__ __launch_bounds__(256) void k3_norms(
    const u16* __restrict__ s1e, const u16* __restrict__ s2e,
    const float* __restrict__ W1, const float* __restrict__ W2,
    float* __restrict__ rn)
{
  const int b = blockIdx.x, lc = blockIdx.y, sent = blockIdx.z;
  const u16* se = sent ? s2e : s1e;
  #pragma unroll
  for (int it = 0; it < 5; ++it) {
    const int idx = it * 256 + (int)threadIdx.x;
    const int l = lc * 32 + idx / 40;
    const int pw = idx % 40;
    const float* Wp = (pw < 20) ? (W1 + pw * 200) : (W2 + (pw - 20) * 200);
    const u16* srow = se + ((long)b * 128 + l) * 200;
    float acc = 0.f;
    #pragma unroll 10
    for (int q = 0; q < 50; ++q) {
      const u16x4 sv = *(const u16x4*)(srow + q * 4);
      const f32x4 wv = *(const f32x4*)(Wp + q * 4);
      #pragma unroll
      for (int u = 0; u < 4; ++u) {
        const float pr = bf2f(f2bf(bf2f(sv[u]) * wv[u]));
        acc += pr * pr;
      }
    }
    rn[(((long)sent * 32 + b) * 128 + l) * 40 + pw] = 1.f / fmaxf(sqrtf(acc), 1e-8f);
  }
}

// ---------------------------------------------------------------------------
// K4: matching. Per (b,p,w): C = (s1.Wp)(s2.Wp)^T via 16x16x32 bf16 MFMA,
//     scale by rnu_i*rnv_j, rowmax -> s1{f,b}, colmax -> s2{f,b}.
// ---------------------------------------------------------------------------
#define LDSS 232
__global__ __launch_bounds__(256, 1) void k4_match(
    const u16* __restrict__ s1e, const u16* __restrict__ s2e,
    const float* __restrict__ W1, const float* __restrict__ W2,
    const float* __restrict__ rn, float* __restrict__ out)
{
  __shared__ __align__(16) u16 aLb[128 * LDSS];
  __shared__ __align__(16) u16 bLb[128 * LDSS];
  __shared__ float rnuL[128], rnvL[128];
  __shared__ float redA[2][128], redB[2][128];
  const int b = blockIdx.x, p = blockIdx.y, w = blockIdx.z;
  const int tid = threadIdx.x;
  const float* Wp = (w ? W2 : W1) + p * 200;
  const u16* s1r = s1e + (long)b * 128 * 200;
  const u16* s2r = s2e + (long)b * 128 * 200;

  for (int idx = tid; idx < 128 * 56; idx += 256) {
    const int row = idx / 56;
    const int k = (idx % 56) * 4;
    u16x4 oa = {0, 0, 0, 0}, ob = {0, 0, 0, 0};
    if (k < 200) {
      const u16x4 sa = *(const u16x4*)(s1r + row * 200 + k);
      const u16x4 sb = *(const u16x4*)(s2r + row * 200 + k);
      const f32x4 wv = *(const f32x4*)(Wp + k);
      #pragma unroll
      for (int u = 0; u < 4; ++u) {
        oa[u] = f2bf(bf2f(sa[u]) * wv[u]);
        ob[u] = f2bf(bf2f(sb[u]) * wv[u]);
      }
    }
    *(u16x4*)(aLb + row * LDSS + k) = oa;
    *(u16x4*)(bLb + row * LDSS + k) = ob;
  }
  if (tid < 128) {
    const int pw = w * 20 + p;
    rnuL[tid] = rn[(((long)0 * 32 + b) * 128 + tid) * 40 + pw];
    rnvL[tid] = rn[(((long)1 * 32 + b) * 128 + tid) * 40 + pw];
  }
  __syncthreads();

  const int lane = tid & 63, wvid = tid >> 6;
  const int wr = wvid >> 1, wc = wvid & 1;
  const int lr = lane & 15, kg = lane >> 4;
  f32x4 acc[4][4];
  #pragma unroll
  for (int mt = 0; mt < 4; ++mt)
    #pragma unroll
    for (int nt = 0; nt < 4; ++nt) acc[mt][nt] = 0.f;

  const u16* a0 = aLb + (64 * wr + lr) * LDSS + kg * 8;
  const u16* b0 = bLb + (64 * wc + lr) * LDSS + kg * 8;
  #pragma unroll
  for (int ks = 0; ks < 7; ++ks) {
    bf16x8 af[4], bfv[4];
    #pragma unroll
    for (int mt = 0; mt < 4; ++mt) af[mt] = *(const bf16x8*)(a0 + mt * 16 * LDSS + ks * 32);
    #pragma unroll
    for (int nt = 0; nt < 4; ++nt) bfv[nt] = *(const bf16x8*)(b0 + nt * 16 * LDSS + ks * 32);
    #pragma unroll
    for (int mt = 0; mt < 4; ++mt)
      #pragma unroll
      for (int nt = 0; nt < 4; ++nt)
        acc[mt][nt] = __builtin_amdgcn_mfma_f32_16x16x32_bf16(af[mt], bfv[nt], acc[mt][nt], 0, 0, 0);
  }

  float ru[4][4], rm[4][4], rv[4], cm[4];
  #pragma unroll
  for (int mt = 0; mt < 4; ++mt)
    #pragma unroll
    for (int r = 0; r < 4; ++r) {
      ru[mt][r] = rnuL[64 * wr + mt * 16 + kg * 4 + r];
      rm[mt][r] = -3.0e38f;
    }
  #pragma unroll
  for (int nt = 0; nt < 4; ++nt) { rv[nt] = rnvL[64 * wc + nt * 16 + lr]; cm[nt] = -3.0e38f; }
  #pragma unroll
  for (int mt = 0; mt < 4; ++mt)
    #pragma unroll
    for (int nt = 0; nt < 4; ++nt)
      #pragma unroll
      for (int r = 0; r < 4; ++r) {
        const float v = acc[mt][nt][r] * ru[mt][r] * rv[nt];
        rm[mt][r] = fmaxf(rm[mt][r], v);
        cm[nt] = fmaxf(cm[nt], v);
      }
  #pragma unroll
  for (int mt = 0; mt < 4; ++mt)
    #pragma unroll
    for (int r = 0; r < 4; ++r) {
      float v = rm[mt][r];
      v = fmaxf(v, __shfl_xor(v, 1, 64));
      v = fmaxf(v, __shfl_xor(v, 2, 64));
      v = fmaxf(v, __shfl_xor(v, 4, 64));
      v = fmaxf(v, __shfl_xor(v, 8, 64));
      rm[mt][r] = v;
    }
  #pragma unroll
  for (int nt = 0; nt < 4; ++nt) {
    float v = cm[nt];
    v = fmaxf(v, __shfl_xor(v, 16, 64));
    v = fmaxf(v, __shfl_xor(v, 32, 64));
    cm[nt] = v;
  }
  if (lr == 0) {
    #pragma unroll
    for (int mt = 0; mt < 4; ++mt)
      #pragma unroll
      for (int r = 0; r < 4; ++r) redA[wc][64 * wr + mt * 16 + kg * 4 + r] = rm[mt][r];
  }
  if (kg == 0) {
    #pragma unroll
    for (int nt = 0; nt < 4; ++nt) redB[wr][64 * wc + nt * 16 + lr] = cm[nt];
  }
  __syncthreads();
  if (tid < 128) {
    const float o1 = fmaxf(redA[0][tid], redA[1][tid]);
    const float o2 = fmaxf(redB[0][tid], redB[1][tid]);
    const long oi = ((long)b * 128 + tid) * 20 + p;
    out[(long)w * 81920 + oi] = o1;
    out[163840 + (long)w * 81920 + oi] = o2;
  }
}

// ---------------------------------------------------------------------------
extern "C" void kernel_launch(void* const* d_in, const int* in_sizes, int n_in,
                              void* d_out, int out_size, void* d_ws, size_t ws_size,
                              hipStream_t stream) {
  const int* tok1 = (const int*)d_in[0];
  const int* tok2 = (const int*)d_in[1];
  const float* embed = (const float*)d_in[2];
  const float* wih0 = (const float*)d_in[3];
  const float* whh0 = (const float*)d_in[4];
  const float* bih0 = (const float*)d_in[5];
  const float* bhh0 = (const float*)d_in[6];
  const float* wih1 = (const float*)d_in[7];
  const float* whh1 = (const float*)d_in[8];
  const float* bih1 = (const float*)d_in[9];
  const float* bhh1 = (const float*)d_in[10];
  const float* wih2 = (const float*)d_in[11];
  const float* whh2 = (const float*)d_in[12];
  const float* bih2 = (const float*)d_in[13];
  const float* bhh2 = (const float*)d_in[14];
  const float* wih3 = (const float*)d_in[15];
  const float* whh3 = (const float*)d_in[16];
  const float* bih3 = (const float*)d_in[17];
  const float* bhh3 = (const float*)d_in[18];
  const float* W1 = (const float*)d_in[19];
  const float* W2 = (const float*)d_in[20];
  float* out = (float*)d_out;

  char* ws = (char*)d_ws;
  const size_t XPROJ_B = 26214400;   // 4*128*12800*4  (xprojP, permuted)
  const size_t SE_B = 1638400;       // 32*128*200*2
  const size_t RN_B = 1310720;       // 2*32*128*40*4
  if (ws_size < XPROJ_B + 2 * SE_B + RN_B) return;
  float* xprojP = (float*)ws;
  u16* s1e = (u16*)(ws + XPROJ_B);
  u16* s2e = (u16*)(ws + XPROJ_B + SE_B);
  float* rn = (float*)(ws + XPROJ_B + 2 * SE_B);

  k1_xproj<<<dim3(32, 4), 256, 0, stream>>>(
      tok1, tok2, embed, wih0, wih1, wih2, wih3,
      bih0, bih1, bih2, bih3, bhh0, bhh1, bhh2, bhh3, xprojP);
  k2_lstm<<<dim3(2, 4), 512, 0, stream>>>(xprojP, whh0, whh1, whh2, whh3, s1e, s2e);
  k3_norms<<<dim3(32, 4, 2), 256, 0, stream>>>(s1e, s2e, W1, W2, rn);
  k4_match<<<dim3(32, 20, 2), 256, 0, stream>>>(s1e, s2e, W1, W2, rn, out);
}

// Round 9
// 275.022 us; speedup vs baseline: 1.6439x; 1.4250x over previous
//
#include <hip/hip_runtime.h>
#include <cstddef>

typedef float f32x4 __attribute__((ext_vector_type(4)));
typedef __bf16 bf16x8 __attribute__((ext_vector_type(8)));
typedef unsigned short u16;
typedef unsigned short u16x4 __attribute__((ext_vector_type(4)));

__device__ __forceinline__ u16 f2bf(float f) {
  unsigned u = __builtin_bit_cast(unsigned, f);
  u += 0x7FFFu + ((u >> 16) & 1u);   // RNE round to bf16
  return (u16)(u >> 16);
}
__device__ __forceinline__ float bf2f(u16 b) {
  unsigned u = ((unsigned)b) << 16;
  return __builtin_bit_cast(float, u);
}
__device__ __forceinline__ float fastrcp(float x) { return __builtin_amdgcn_rcpf(x); }

// Raw barrier: LDS-only drain (lgkmcnt), NO vmcnt drain. sched_barrier(0)
// stops post-barrier code hoisting (rule #18).
__device__ __forceinline__ void wg_barrier() {
  asm volatile("s_waitcnt lgkmcnt(0)" ::: "memory");
  __builtin_amdgcn_s_barrier();
  __builtin_amdgcn_sched_barrier(0);
}

// ---------------------------------------------------------------------------
// K1: xprojP[dir][l][j(100)][b(32)][r(4)] = e(tok[b][l]).wih[n] + bias,
//     n = r*100 + j.  Chunk rows remapped so nt == r: each lane's 4 nt-accs
//     form the (j,b) r-vector in-register; per-wave swizzled LDS transpose
//     then 1KB-contiguous dwordx4 stores (fixes the 4B-scatter store flood).
//     Grid: (32 l-groups, 4 dirs, 2 n-halves) = 256 wgs.
// ---------------------------------------------------------------------------
#define K1_LDA 328
__global__ __launch_bounds__(256) void k1_xproj(
    const int* __restrict__ tok1, const int* __restrict__ tok2,
    const float* __restrict__ embed,
    const float* __restrict__ wihA, const float* __restrict__ wihB,
    const float* __restrict__ wihC, const float* __restrict__ wihD,
    const float* __restrict__ bihA, const float* __restrict__ bihB,
    const float* __restrict__ bihC, const float* __restrict__ bihD,
    const float* __restrict__ bhhA, const float* __restrict__ bhhB,
    const float* __restrict__ bhhC, const float* __restrict__ bhhD,
    float* __restrict__ xprojP)
{
  __shared__ __align__(16) u16 aL[128 * K1_LDA];   // 84.0 KB
  __shared__ __align__(16) u16 bL[64 * K1_LDA];    // 42.0 KB
  __shared__ __align__(16) float tp[4 * 2048];     // 32.0 KB (per-wave transpose)
  const int dir = blockIdx.y;
  const int z = blockIdx.z;                        // n-half: 0 -> nc 0..3, 1 -> nc 4..6
  const float* wih = (dir == 0) ? wihA : (dir == 1) ? wihB : (dir == 2) ? wihC : wihD;
  const float* bih = (dir == 0) ? bihA : (dir == 1) ? bihB : (dir == 2) ? bihC : bihD;
  const float* bhh = (dir == 0) ? bhhA : (dir == 1) ? bhhB : (dir == 2) ? bhhC : bhhD;
  const int* tok = (dir < 2) ? tok1 : tok2;
  const int lb = blockIdx.x * 4;
  const int tid = threadIdx.x;
  char* tpb = (char*)tp;

  #pragma unroll
  for (int it = 0; it < 40; ++it) {            // A: 128 rows (l,b), K pad 320
    const int idx = it * 256 + tid;
    const int row = idx / 80, k = (idx % 80) * 4;
    u16x4 o = {0, 0, 0, 0};
    if (k < 300) {
      const int bb = row & 31, ll = lb + (row >> 5);
      const long ar = (long)tok[bb * 128 + ll] * 300;
      const f32x4 v = *(const f32x4*)(embed + ar + k);
      o[0] = f2bf(v[0]); o[1] = f2bf(v[1]); o[2] = f2bf(v[2]); o[3] = f2bf(v[3]);
    }
    *(u16x4*)(aL + row * K1_LDA + k) = o;
  }

  const int lane = tid & 63, w = tid >> 6;
  const int lr = lane & 15, kg = lane >> 4;
  const u16* a0 = aL + (w * 32 + lr) * K1_LDA + kg * 8;
  const u16* b0 = bL + lr * K1_LDA + kg * 8;
  const int l = lb + w;
  const int nch = z ? 3 : 4;

  for (int c = 0; c < nch; ++c) {
    const int nc = z * 4 + c;
    __syncthreads();
    // stage B chunk, REMAPPED rows: rowidx = r*16 + (j - nc*16), n = r*100 + j
    #pragma unroll
    for (int it = 0; it < 20; ++it) {
      const int idx = it * 256 + tid;
      const int row = idx / 80, k = (idx % 80) * 4;
      const int j = nc * 16 + (row & 15);
      const int n = (row >> 4) * 100 + j;
      u16x4 o = {0, 0, 0, 0};
      if (k < 300 && j < 100) {
        const f32x4 v = *(const f32x4*)(wih + (long)n * 300 + k);
        o[0] = f2bf(v[0]); o[1] = f2bf(v[1]); o[2] = f2bf(v[2]); o[3] = f2bf(v[3]);
      }
      *(u16x4*)(bL + row * K1_LDA + k) = o;
    }
    __syncthreads();

    f32x4 acc[2][4];
    #pragma unroll
    for (int mt = 0; mt < 2; ++mt)
      #pragma unroll
      for (int nt = 0; nt < 4; ++nt) acc[mt][nt] = 0.f;
    #pragma unroll
    for (int ks = 0; ks < 10; ++ks) {
      bf16x8 af[2], bfv[4];
      #pragma unroll
      for (int mt = 0; mt < 2; ++mt) af[mt] = *(const bf16x8*)(a0 + mt * 16 * K1_LDA + ks * 32);
      #pragma unroll
      for (int nt = 0; nt < 4; ++nt) bfv[nt] = *(const bf16x8*)(b0 + nt * 16 * K1_LDA + ks * 32);
      #pragma unroll
      for (int mt = 0; mt < 2; ++mt)
        #pragma unroll
        for (int nt = 0; nt < 4; ++nt)
          acc[mt][nt] = __builtin_amdgcn_mfma_f32_16x16x32_bf16(af[mt], bfv[nt], acc[mt][nt], 0, 0, 0);
    }

    // epilogue: in-lane r-vector (nt == r) + swizzled per-wave LDS transpose
    const int jl = nc * 16 + lr;
    float bias[4];
    #pragma unroll
    for (int nt = 0; nt < 4; ++nt)
      bias[nt] = (jl < 100) ? (bih[nt * 100 + jl] + bhh[nt * 100 + jl]) : 0.f;
    #pragma unroll
    for (int mt = 0; mt < 2; ++mt)
      #pragma unroll
      for (int rr = 0; rr < 4; ++rr) {
        f32x4 v;
        #pragma unroll
        for (int nt = 0; nt < 4; ++nt) v[nt] = acc[mt][nt][rr] + bias[nt];
        const int b = 16 * mt + 4 * kg + rr;
        const int g = lr * 32 + (b ^ (lr & 7));      // swizzled granule
        *(f32x4*)(tpb + w * 8192 + g * 16) = v;
      }
    asm volatile("s_waitcnt lgkmcnt(0)" ::: "memory");
    #pragma unroll
    for (int i = 0; i < 8; ++i) {
      const int fl = i * 64 + lane;                  // lane-contiguous stores
      const int jloc = fl >> 5, bb = fl & 31;
      const int g = jloc * 32 + (bb ^ (jloc & 7));
      const f32x4 v = *(const f32x4*)(tpb + w * 8192 + g * 16);
      const int j = nc * 16 + jloc;
      if (j < 100)
        *(f32x4*)(xprojP + ((long)(dir * 128 + l) * 100 + j) * 128 + bb * 4) = v;
    }
  }
}

// ---------------------------------------------------------------------------
// K2: recurrent LSTM, batched MFMA, gate-interleaved whh rows.
//   Gates now division-free: v_rcp_f32 + merged denominators
//   (5 exp + 2 rcp per gate-set instead of 5 exp + 10 precise-divides).
// ---------------------------------------------------------------------------
__device__ __forceinline__ bf16x8 frag_ld(const float* __restrict__ whh,
                                          int mt, int ks, int lr, int kg) {
  bf16x8 f;
  const int orow = (lr & 3) * 100 + mt * 4 + (lr >> 2);
  #pragma unroll
  for (int u = 0; u < 8; ++u) {
    const int k = ks * 32 + kg * 8 + u;
    const float v = (mt < 25 && k < 100) ? whh[(long)orow * 100 + k] : 0.f;
    f[u] = (__bf16)bf2f(f2bf(v));
  }
  return f;
}

#define K2_MFMA4(A_, F0_, F1_, F2_, F3_)                                    \
  A_ = __builtin_amdgcn_mfma_f32_16x16x32_bf16(F0_, hb0, A_, 0, 0, 0);      \
  A_ = __builtin_amdgcn_mfma_f32_16x16x32_bf16(F1_, hb1, A_, 0, 0, 0);      \
  A_ = __builtin_amdgcn_mfma_f32_16x16x32_bf16(F2_, hb2, A_, 0, 0, 0);      \
  A_ = __builtin_amdgcn_mfma_f32_16x16x32_bf16(F3_, hb3, A_, 0, 0, 0);

// cc' = sig(f)*cc + sig(i)*tanh(g);  h = sig(o)*tanh(cc')
// sig(x) = E/(1+E), tanh(y) = (E2-1)/(E2+1) with E = e^x, E2 = e^{2y}.
// Merged: one rcp for the cc' update, one for h.
#define K2_GATE(A_, CC_, WRO_, WBUF_)                                       \
  {                                                                         \
    const float Ei = __expf(A_[0]);                                         \
    const float Ef = __expf(A_[1]);                                         \
    const float Eg = __expf(2.0f * A_[2]);                                  \
    const float pf = 1.0f + Ef, pi = 1.0f + Ei, pg = Eg + 1.0f;             \
    const float d_ = fastrcp(pf * pi * pg);                                 \
    CC_ = (Ef * CC_ * pi * pg + Ei * (Eg - 1.0f) * pf) * d_;                \
    const float Eo = __expf(A_[3]);                                         \
    const float Ec = __expf(2.0f * CC_);                                    \
    const float h_ = Eo * (Ec - 1.0f) * fastrcp((1.0f + Eo) * (Ec + 1.0f)); \
    *(u16*)(hby + (WRO_) + (WBUF_) * 4096) = f2bf(h_);                      \
  }

// step: reads buf RB_, writes buf RB_^1; consumes XA*, prefetches t+2 into XA*
#define K2_STEP(RB_, XA0, XA1, XA2, XA3)                                    \
  {                                                                         \
    bf16x8 hb0 = *(const bf16x8*)(hby + rd0 + (RB_) * 4096);                \
    bf16x8 hb1 = *(const bf16x8*)(hby + rd1 + (RB_) * 4096);                \
    bf16x8 hb2 = *(const bf16x8*)(hby + rd2 + (RB_) * 4096);                \
    bf16x8 hb3 = *(const bf16x8*)(hby + rd3 + (RB_) * 4096);                \
    f32x4 a0 = XA0, a1 = XA1, a2 = XA2, a3 = XA3;                           \
    XA0 = *(const f32x4*)(pstep + off0);                                    \
    XA1 = *(const f32x4*)(pstep + off1);                                    \
    XA2 = *(const f32x4*)(pstep + off2);                                    \
    if (wave == 0) XA3 = *(const f32x4*)(pstep + off3);                     \
    pstep += dstep;                                                         \
    K2_MFMA4(a0, f00, f01, f02, f03)                                        \
    K2_MFMA4(a1, f10, f11, f12, f13)                                        \
    K2_MFMA4(a2, f20, f21, f22, f23)                                        \
    if (wave == 0) { K2_MFMA4(a3, f30, f31, f32, f33) }                     \
    K2_GATE(a0, cc0, wr0, (RB_) ^ 1)                                        \
    K2_GATE(a1, cc1, wr1, (RB_) ^ 1)                                        \
    K2_GATE(a2, cc2, wr2, (RB_) ^ 1)                                        \
    if (wave == 0) { K2_GATE(a3, cc3, wr3, (RB_) ^ 1) }                     \
  }

#define K2_COPY(TA_, CB_)                                                   \
  if (cact) {                                                               \
    const unsigned v_ = *(const unsigned*)(hby + cprd + (CB_) * 4096);      \
    const unsigned v2_ = *(const unsigned*)(hby + cprd + 2048 + (CB_) * 4096); \
    seD[cpbase + (TA_) * 100] = v_;                                         \
    seD[cpbase2 + (TA_) * 100] = v2_;                                       \
  }

__global__ __launch_bounds__(512, 1) void k2_lstm(
    const float* __restrict__ xprojP,
    const float* __restrict__ whhA, const float* __restrict__ whhB,
    const float* __restrict__ whhC, const float* __restrict__ whhD,
    u16* __restrict__ s1e, u16* __restrict__ s2e)
{
  const int bh = blockIdx.x;                 // batch half
  const int dir = blockIdx.y;
  const float* whh = (dir == 0) ? whhA : (dir == 1) ? whhB : (dir == 2) ? whhC : whhD;
  const int tid = threadIdx.x;
  const int lane = tid & 63, wave = tid >> 6;
  const int lr = lane & 15, kg = lane >> 4;
  const int mt0 = wave, mt1 = wave + 8, mt2 = wave + 16, mt3 = wave + 24;

  __shared__ __align__(16) u16 hraw[2 * 16 * 128];   // [buf][b=16][k=128], swizzled
  char* hby = (char*)hraw;

  bf16x8 f00 = frag_ld(whh, mt0, 0, lr, kg), f01 = frag_ld(whh, mt0, 1, lr, kg),
         f02 = frag_ld(whh, mt0, 2, lr, kg), f03 = frag_ld(whh, mt0, 3, lr, kg);
  bf16x8 f10 = frag_ld(whh, mt1, 0, lr, kg), f11 = frag_ld(whh, mt1, 1, lr, kg),
         f12 = frag_ld(whh, mt1, 2, lr, kg), f13 = frag_ld(whh, mt1, 3, lr, kg);
  bf16x8 f20 = frag_ld(whh, mt2, 0, lr, kg), f21 = frag_ld(whh, mt2, 1, lr, kg),
         f22 = frag_ld(whh, mt2, 2, lr, kg), f23 = frag_ld(whh, mt2, 3, lr, kg);
  bf16x8 f30 = frag_ld(whh, mt3, 0, lr, kg), f31 = frag_ld(whh, mt3, 1, lr, kg),
         f32 = frag_ld(whh, mt3, 2, lr, kg), f33 = frag_ld(whh, mt3, 3, lr, kg);

  for (int idx = tid; idx < 2 * 16 * 128; idx += 512) hraw[idx] = 0;

  const int e7 = lr & 7;
  const int rd0 = lr * 256 + ((kg ^ e7) * 16);
  const int rd1 = lr * 256 + (((4 + kg) ^ e7) * 16);
  const int rd2 = lr * 256 + (((8 + kg) ^ e7) * 16);
  const int rd3 = lr * 256 + (((12 + kg) ^ e7) * 16);
  const int wr0 = lr * 256 + (((mt0 >> 1) ^ e7) * 16) + ((mt0 & 1) * 4 + kg) * 2;
  const int wr1 = lr * 256 + (((mt1 >> 1) ^ e7) * 16) + ((mt1 & 1) * 4 + kg) * 2;
  const int wr2 = lr * 256 + (((mt2 >> 1) ^ e7) * 16) + ((mt2 & 1) * 4 + kg) * 2;
  const int wr3 = lr * 256 + (((mt3 >> 1) ^ e7) * 16) + ((mt3 & 1) * 4 + kg) * 2;

  const bool cact = (tid < 400);
  const int cb = tid / 50, cj2 = tid - cb * 50;
  const int cprd = cb * 256 + (((cj2 >> 2) ^ (cb & 7)) * 16) + (cj2 & 3) * 4;
  const bool bwd = (dir & 1);
  unsigned* seD = (unsigned*)((dir < 2) ? s1e : s2e);
  const long cpbase = ((long)(bh * 16 + cb) * 128) * 100 + (bwd ? 50 : 0) + cj2;
  const long cpbase2 = cpbase + (long)8 * 128 * 100;

  const float* pbase = xprojP + (long)dir * 128 * 12800;
  const int off0 = ((mt0 * 4 + kg) * 32 + bh * 16 + lr) * 4;
  const int off1 = ((mt1 * 4 + kg) * 32 + bh * 16 + lr) * 4;
  const int off2 = ((mt2 * 4 + kg) * 32 + bh * 16 + lr) * 4;
  const int off3 = ((mt3 * 4 + kg) * 32 + bh * 16 + lr) * 4;
  const long dstep = bwd ? -12800 : 12800;
  const float* pstep = pbase + (long)(bwd ? 125 : 2) * 12800;

  f32x4 xa0, xa1, xa2, xa3, xb0, xb1, xb2, xb3;
  {
    const float* p0 = pbase + (long)(bwd ? 127 : 0) * 12800;
    const float* p1 = pbase + (long)(bwd ? 126 : 1) * 12800;
    xa0 = *(const f32x4*)(p0 + off0); xa1 = *(const f32x4*)(p0 + off1);
    xa2 = *(const f32x4*)(p0 + off2);
    xb0 = *(const f32x4*)(p1 + off0); xb1 = *(const f32x4*)(p1 + off1);
    xb2 = *(const f32x4*)(p1 + off2);
    xa3 = xb3 = f32x4{0.f, 0.f, 0.f, 0.f};
    if (wave == 0) { xa3 = *(const f32x4*)(p0 + off3); xb3 = *(const f32x4*)(p1 + off3); }
  }
  float cc0 = 0.f, cc1 = 0.f, cc2 = 0.f, cc3 = 0.f;
  __syncthreads();

  #pragma unroll 1
  for (int tt = 0; tt < 64; ++tt) {
    const int te = 2 * tt, to = 2 * tt + 1;
    K2_STEP(0, xa0, xa1, xa2, xa3)             // reads buf0, writes buf1
    wg_barrier();
    K2_COPY(bwd ? 127 - te : te, 1)
    K2_STEP(1, xb0, xb1, xb2, xb3)             // reads buf1, writes buf0
    wg_barrier();
    K2_COPY(bwd ? 127 - to : to, 0)
  }
}

// ---------------------------------------------------------------------------
// K3: reciprocal norms rn[sent][b][l][w*20+p] = 1/max(||bf16(s_d*W_pd)||, 1e-8)
// ---------------------------------------------------------------------------
__global__ __launch_bounds__(256) void k3_norms(
    const u16* __restrict__ s1e, const u16* __restrict__ s2e,
    const float* __restrict__ W1, const float* __restrict__ W2,
    float* __restrict__ rn)
{
  const int b = blockIdx.x, lc = blockIdx.y, sent = blockIdx.z;
  const u16* se = sent ? s2e : s1e;
  #pragma unroll
  for (int it = 0; it < 5; ++it) {
    const int idx = it * 256 + (int)threadIdx.x;
    const int l = lc * 32 + idx / 40;
    const int pw = idx % 40;
    const float* Wp = (pw < 20) ? (W1 + pw * 200) : (W2 + (pw - 20) * 200);
    const u16* srow = se + ((long)b * 128 + l) * 200;
    float acc = 0.f;
    #pragma unroll 10
    for (int q = 0; q < 50; ++q) {
      const u16x4 sv = *(const u16x4*)(srow + q * 4);
      const f32x4 wv = *(const f32x4*)(Wp + q * 4);
      #pragma unroll
      for (int u = 0; u < 4; ++u) {
        const float pr = bf2f(f2bf(bf2f(sv[u]) * wv[u]));
        acc += pr * pr;
      }
    }
    rn[(((long)sent * 32 + b) * 128 + l) * 40 + pw] = 1.f / fmaxf(sqrtf(acc), 1e-8f);
  }
}

// ---------------------------------------------------------------------------
// K4: matching. Per (b,p,w): C = (s1.Wp)(s2.Wp)^T via 16x16x32 bf16 MFMA,
//     scale by rnu_i*rnv_j, rowmax -> s1{f,b}, colmax -> s2{f,b}.
// ---------------------------------------------------------------------------
#define LDSS 232
__global__ __launch_bounds__(256, 1) void k4_match(
    const u16* __restrict__ s1e, const u16* __restrict__ s2e,
    const float* __restrict__ W1, const float* __restrict__ W2,
    const float* __restrict__ rn, float* __restrict__ out)
{
  __shared__ __align__(16) u16 aLb[128 * LDSS];
  __shared__ __align__(16) u16 bLb[128 * LDSS];
  __shared__ float rnuL[128], rnvL[128];
  __shared__ float redA[2][128], redB[2][128];
  const int b = blockIdx.x, p = blockIdx.y, w = blockIdx.z;
  const int tid = threadIdx.x;
  const float* Wp = (w ? W2 : W1) + p * 200;
  const u16* s1r = s1e + (long)b * 128 * 200;
  const u16* s2r = s2e + (long)b * 128 * 200;

  for (int idx = tid; idx < 128 * 56; idx += 256) {
    const int row = idx / 56;
    const int k = (idx % 56) * 4;
    u16x4 oa = {0, 0, 0, 0}, ob = {0, 0, 0, 0};
    if (k < 200) {
      const u16x4 sa = *(const u16x4*)(s1r + row * 200 + k);
      const u16x4 sb = *(const u16x4*)(s2r + row * 200 + k);
      const f32x4 wv = *(const f32x4*)(Wp + k);
      #pragma unroll
      for (int u = 0; u < 4; ++u) {
        oa[u] = f2bf(bf2f(sa[u]) * wv[u]);
        ob[u] = f2bf(bf2f(sb[u]) * wv[u]);
      }
    }
    *(u16x4*)(aLb + row * LDSS + k) = oa;
    *(u16x4*)(bLb + row * LDSS + k) = ob;
  }
  if (tid < 128) {
    const int pw = w * 20 + p;
    rnuL[tid] = rn[(((long)0 * 32 + b) * 128 + tid) * 40 + pw];
    rnvL[tid] = rn[(((long)1 * 32 + b) * 128 + tid) * 40 + pw];
  }
  __syncthreads();

  const int lane = tid & 63, wvid = tid >> 6;
  const int wr = wvid >> 1, wc = wvid & 1;
  const int lr = lane & 15, kg = lane >> 4;
  f32x4 acc[4][4];
  #pragma unroll
  for (int mt = 0; mt < 4; ++mt)
    #pragma unroll
    for (int nt = 0; nt < 4; ++nt) acc[mt][nt] = 0.f;

  const u16* a0 = aLb + (64 * wr + lr) * LDSS + kg * 8;
  const u16* b0 = bLb + (64 * wc + lr) * LDSS + kg * 8;
  #pragma unroll
  for (int ks = 0; ks < 7; ++ks) {
    bf16x8 af[4], bfv[4];
    #pragma unroll
    for (int mt = 0; mt < 4; ++mt) af[mt] = *(const bf16x8*)(a0 + mt * 16 * LDSS + ks * 32);
    #pragma unroll
    for (int nt = 0; nt < 4; ++nt) bfv[nt] = *(const bf16x8*)(b0 + nt * 16 * LDSS + ks * 32);
    #pragma unroll
    for (int mt = 0; mt < 4; ++mt)
      #pragma unroll
      for (int nt = 0; nt < 4; ++nt)
        acc[mt][nt] = __builtin_amdgcn_mfma_f32_16x16x32_bf16(af[mt], bfv[nt], acc[mt][nt], 0, 0, 0);
  }

  float ru[4][4], rm[4][4], rv[4], cm[4];
  #pragma unroll
  for (int mt = 0; mt < 4; ++mt)
    #pragma unroll
    for (int r = 0; r < 4; ++r) {
      ru[mt][r] = rnuL[64 * wr + mt * 16 + kg * 4 + r];
      rm[mt][r] = -3.0e38f;
    }
  #pragma unroll
  for (int nt = 0; nt < 4; ++nt) { rv[nt] = rnvL[64 * wc + nt * 16 + lr]; cm[nt] = -3.0e38f; }
  #pragma unroll
  for (int mt = 0; mt < 4; ++mt)
    #pragma unroll
    for (int nt = 0; nt < 4; ++nt)
      #pragma unroll
      for (int r = 0; r < 4; ++r) {
        const float v = acc[mt][nt][r] * ru[mt][r] * rv[nt];
        rm[mt][r] = fmaxf(rm[mt][r], v);
        cm[nt] = fmaxf(cm[nt], v);
      }
  #pragma unroll
  for (int mt = 0; mt < 4; ++mt)
    #pragma unroll
    for (int r = 0; r < 4; ++r) {
      float v = rm[mt][r];
      v = fmaxf(v, __shfl_xor(v, 1, 64));
      v = fmaxf(v, __shfl_xor(v, 2, 64));
      v = fmaxf(v, __shfl_xor(v, 4, 64));
      v = fmaxf(v, __shfl_xor(v, 8, 64));
      rm[mt][r] = v;
    }
  #pragma unroll
  for (int nt = 0; nt < 4; ++nt) {
    float v = cm[nt];
    v = fmaxf(v, __shfl_xor(v, 16, 64));
    v = fmaxf(v, __shfl_xor(v, 32, 64));
    cm[nt] = v;
  }
  if (lr == 0) {
    #pragma unroll
    for (int mt = 0; mt < 4; ++mt)
      #pragma unroll
      for (int r = 0; r < 4; ++r) redA[wc][64 * wr + mt * 16 + kg * 4 + r] = rm[mt][r];
  }
  if (kg == 0) {
    #pragma unroll
    for (int nt = 0; nt < 4; ++nt) redB[wr][64 * wc + nt * 16 + lr] = cm[nt];
  }
  __syncthreads();
  if (tid < 128) {
    const float o1 = fmaxf(redA[0][tid], redA[1][tid]);
    const float o2 = fmaxf(redB[0][tid], redB[1][tid]);
    const long oi = ((long)b * 128 + tid) * 20 + p;
    out[(long)w * 81920 + oi] = o1;
    out[163840 + (long)w * 81920 + oi] = o2;
  }
}

// ---------------------------------------------------------------------------
extern "C" void kernel_launch(void* const* d_in, const int* in_sizes, int n_in,
                              void* d_out, int out_size, void* d_ws, size_t ws_size,
                              hipStream_t stream) {
  const int* tok1 = (const int*)d_in[0];
  const int* tok2 = (const int*)d_in[1];
  const float* embed = (const float*)d_in[2];
  const float* wih0 = (const float*)d_in[3];
  const float* whh0 = (const float*)d_in[4];
  const float* bih0 = (const float*)d_in[5];
  const float* bhh0 = (const float*)d_in[6];
  const float* wih1 = (const float*)d_in[7];
  const float* whh1 = (const float*)d_in[8];
  const float* bih1 = (const float*)d_in[9];
  const float* bhh1 = (const float*)d_in[10];
  const float* wih2 = (const float*)d_in[11];
  const float* whh2 = (const float*)d_in[12];
  const float* bih2 = (const float*)d_in[13];
  const float* bhh2 = (const float*)d_in[14];
  const float* wih3 = (const float*)d_in[15];
  const float* whh3 = (const float*)d_in[16];
  const float* bih3 = (const float*)d_in[17];
  const float* bhh3 = (const float*)d_in[18];
  const float* W1 = (const float*)d_in[19];
  const float* W2 = (const float*)d_in[20];
  float* out = (float*)d_out;

  char* ws = (char*)d_ws;
  const size_t XPROJ_B = 26214400;   // 4*128*12800*4  (xprojP, permuted)
  const size_t SE_B = 1638400;       // 32*128*200*2
  const size_t RN_B = 1310720;       // 2*32*128*40*4
  if (ws_size < XPROJ_B + 2 * SE_B + RN_B) return;
  float* xprojP = (float*)ws;
  u16* s1e = (u16*)(ws + XPROJ_B);
  u16* s2e = (u16*)(ws + XPROJ_B + SE_B);
  float* rn = (float*)(ws + XPROJ_B + 2 * SE_B);

  k1_xproj<<<dim3(32, 4, 2), 256, 0, stream>>>(
      tok1, tok2, embed, wih0, wih1, wih2, wih3,
      bih0, bih1, bih2, bih3, bhh0, bhh1, bhh2, bhh3, xprojP);
  k2_lstm<<<dim3(2, 4), 512, 0, stream>>>(xprojP, whh0, whh1, whh2, whh3, s1e, s2e);
  k3_norms<<<dim3(32, 4, 2), 256, 0, stream>>>(s1e, s2e, W1, W2, rn);
  k4_match<<<dim3(32, 20, 2), 256, 0, stream>>>(s1e, s2e, W1, W2, rn, out);
}